// Round 1
// baseline (1321.723 us; speedup 1.0000x reference)
//
#include <hip/hip_runtime.h>
#include <hip/hip_bf16.h>
#include <math.h>

// RWKV-7 Tmix: B=2, T=1024, C=1024, H=16, N=64
constexpr int Bb = 2, Tt = 1024, Cc = 1024, Hh = 16, Nn = 64;
constexpr int Mtot = Bb * Tt;          // 2048 rows
constexpr int PACKW = 6 * Nn;          // 384 floats per (b,h,t): r,wdec,kmod,v,-kk,kk*a
constexpr int SL_R = 0, SL_W = 1, SL_K = 2, SL_V = 3, SL_NK = 4, SL_BV = 5;

__device__ __forceinline__ float sigf(float x) { return 1.f / (1.f + expf(-x)); }

// ---------------------------------------------------------------------------
// Generic tiled f32 GEMM: C[M,N] = epi(bias + A'[M,K] @ W[K,N])
// MIX: A'[m,k] = x[m,k] + (x[m-1,k or 0] - x[m,k]) * mixv[k]   (time-shift mix)
// OUTM==0: row-major out[m*N+n]; OUTM==1: scatter into pack layout slot.
// ---------------------------------------------------------------------------
template <int BM, int BN, int BK, int TM, int TN, int MIX, int BIAS, int EPI, int OUTM>
__global__ __launch_bounds__((BM / TM) * (BN / TN)) void gemm_k(
    const float* __restrict__ A, const float* __restrict__ W,
    const float* __restrict__ mixv, const float* __restrict__ bias,
    float* __restrict__ out, int M, int Ncol, int K, int slot)
{
    constexpr int NT = (BM / TM) * (BN / TN);
    constexpr int A4 = BM * BK / 4;
    constexpr int B4 = BK * BN / 4;
    __shared__ float As[BK][BM + 4];
    __shared__ float Bs[BK][BN];
    const int tid = threadIdx.x;
    const int bm = blockIdx.y * BM;
    const int bn = blockIdx.x * BN;
    const int tx = tid % (BN / TN);
    const int ty = tid / (BN / TN);

    float acc[TM][TN];
#pragma unroll
    for (int i = 0; i < TM; i++)
#pragma unroll
        for (int j = 0; j < TN; j++) acc[i][j] = 0.f;

    for (int k0 = 0; k0 < K; k0 += BK) {
        // --- load A tile (BM x BK), transposed into As[k][m]
        for (int i = tid; i < A4; i += NT) {
            int row = i / (BK / 4), kq = i % (BK / 4);
            int m = bm + row, kb = k0 + kq * 4;
            float4 xv = *(const float4*)(A + (size_t)m * K + kb);
            if (MIX) {
                int t = m & (Tt - 1);
                float4 xp = make_float4(0.f, 0.f, 0.f, 0.f);
                if (t) xp = *(const float4*)(A + (size_t)(m - 1) * K + kb);
                float4 mv = *(const float4*)(mixv + kb);
                xv.x += (xp.x - xv.x) * mv.x;
                xv.y += (xp.y - xv.y) * mv.y;
                xv.z += (xp.z - xv.z) * mv.z;
                xv.w += (xp.w - xv.w) * mv.w;
            }
            As[kq * 4 + 0][row] = xv.x;
            As[kq * 4 + 1][row] = xv.y;
            As[kq * 4 + 2][row] = xv.z;
            As[kq * 4 + 3][row] = xv.w;
        }
        // --- load B tile (BK x BN)
        for (int i = tid; i < B4; i += NT) {
            int kr = i / (BN / 4), nq = i % (BN / 4);
            float4 wv = *(const float4*)(W + (size_t)(k0 + kr) * Ncol + bn + nq * 4);
            *(float4*)&Bs[kr][nq * 4] = wv;
        }
        __syncthreads();
#pragma unroll
        for (int kk = 0; kk < BK; kk++) {
            float av[TM], bv[TN];
#pragma unroll
            for (int i = 0; i < TM; i += 4) {
                float4 t4 = *(const float4*)&As[kk][ty * TM + i];
                av[i] = t4.x; av[i + 1] = t4.y; av[i + 2] = t4.z; av[i + 3] = t4.w;
            }
#pragma unroll
            for (int j = 0; j < TN; j += 4) {
                float4 t4 = *(const float4*)&Bs[kk][tx * TN + j];
                bv[j] = t4.x; bv[j + 1] = t4.y; bv[j + 2] = t4.z; bv[j + 3] = t4.w;
            }
#pragma unroll
            for (int i = 0; i < TM; i++)
#pragma unroll
                for (int j = 0; j < TN; j++) acc[i][j] += av[i] * bv[j];
        }
        __syncthreads();
    }

#pragma unroll
    for (int i = 0; i < TM; i++) {
        int m = bm + ty * TM + i;
#pragma unroll
        for (int j = 0; j < TN; j++) {
            int n = bn + tx * TN + j;
            float c = acc[i][j];
            if (BIAS) c += bias[n];
            if (EPI == 1) c = tanhf(c);
            else if (EPI == 2) c = sigf(c);
            else if (EPI == 3) c = expf(-expf(c));
            if (OUTM == 0) {
                out[(size_t)m * Ncol + n] = c;
            } else {
                int b = m >> 10, t = m & (Tt - 1);
                int h = n >> 6, nn2 = n & 63;
                out[((size_t)(b * Hh + h) * Tt + t) * PACKW + slot * Nn + nn2] = c;
            }
        }
    }
}

// ---------------------------------------------------------------------------
// prep: per (b,t,h) head of 64 channels, one lane per channel.
// Reads raw k (SL_K) and a (SL_BV); writes kmod->SL_K, -kk->SL_NK, kk*a->SL_BV.
// ---------------------------------------------------------------------------
__global__ __launch_bounds__(256) void prep_k(float* __restrict__ pk,
                                              const float* __restrict__ k_k,
                                              const float* __restrict__ k_a)
{
    int inst = blockIdx.x * 4 + (threadIdx.x >> 6);  // 0..B*T*H-1
    int lane = threadIdx.x & 63;
    int b = inst >> 14;
    int rem = inst & 16383;
    int t = rem >> 4;
    int h = rem & 15;
    size_t base = ((size_t)(b * Hh + h) * Tt + t) * PACKW;
    int c = h * 64 + lane;
    float kraw = pk[base + SL_K * 64 + lane];
    float a = pk[base + SL_BV * 64 + lane];
    float kkv = kraw * k_k[c];
    float ss = kkv * kkv;
#pragma unroll
    for (int m = 1; m < 64; m <<= 1) ss += __shfl_xor(ss, m);
    float kkn = kkv / fmaxf(sqrtf(ss), 1e-12f);
    pk[base + SL_NK * 64 + lane] = -kkn;
    pk[base + SL_BV * 64 + lane] = kkn * a;
    pk[base + SL_K * 64 + lane] = kraw * (1.f + (a - 1.f) * k_a[c]);
}

// ---------------------------------------------------------------------------
// WKV scan. One wave handles 8 state rows of one (b,h); lane = (row, 8-col grp).
// State S[i][j] in registers; per-t vectors read from pack with 2-deep prefetch.
// ---------------------------------------------------------------------------
struct Frag {
    float4 r0, r1, w0, w1, k0, k1, n0, n1, b0, b1;
    float v;
};

__device__ __forceinline__ Frag loadfrag(const float* __restrict__ p, int j0, int i)
{
    Frag f;
    f.r0 = *(const float4*)(p + SL_R * 64 + j0);  f.r1 = *(const float4*)(p + SL_R * 64 + j0 + 4);
    f.w0 = *(const float4*)(p + SL_W * 64 + j0);  f.w1 = *(const float4*)(p + SL_W * 64 + j0 + 4);
    f.k0 = *(const float4*)(p + SL_K * 64 + j0);  f.k1 = *(const float4*)(p + SL_K * 64 + j0 + 4);
    f.n0 = *(const float4*)(p + SL_NK * 64 + j0); f.n1 = *(const float4*)(p + SL_NK * 64 + j0 + 4);
    f.b0 = *(const float4*)(p + SL_BV * 64 + j0); f.b1 = *(const float4*)(p + SL_BV * 64 + j0 + 4);
    f.v = p[SL_V * 64 + i];
    return f;
}

__device__ __forceinline__ float dot8(const float S[8], float4 a, float4 b)
{
    return S[0] * a.x + S[1] * a.y + S[2] * a.z + S[3] * a.w +
           S[4] * b.x + S[5] * b.y + S[6] * b.z + S[7] * b.w;
}

__device__ __forceinline__ void upd4(float* S, float4 w, float4 bv, float4 km, float sa, float v)
{
    S[0] = S[0] * w.x + (sa * bv.x + v * km.x);
    S[1] = S[1] * w.y + (sa * bv.y + v * km.y);
    S[2] = S[2] * w.z + (sa * bv.z + v * km.z);
    S[3] = S[3] * w.w + (sa * bv.w + v * km.w);
}

__device__ __forceinline__ void stepf(float S[8], const Frag& f, int jb, float* optr)
{
    float sa = dot8(S, f.n0, f.n1);
    sa += __shfl_xor(sa, 1); sa += __shfl_xor(sa, 2); sa += __shfl_xor(sa, 4);
    upd4(S, f.w0, f.b0, f.k0, sa, f.v);
    upd4(S + 4, f.w1, f.b1, f.k1, sa, f.v);
    float ot = dot8(S, f.r0, f.r1);
    ot += __shfl_xor(ot, 1); ot += __shfl_xor(ot, 2); ot += __shfl_xor(ot, 4);
    if (jb == 0) *optr = ot;
}

__global__ __launch_bounds__(256) void wkv_k(const float* __restrict__ pk, float* __restrict__ o)
{
    const int gw = blockIdx.x * 4 + (threadIdx.x >> 6);
    const int bh = gw >> 3, rg = gw & 7;
    const int lane = threadIdx.x & 63;
    const int ri = lane >> 3, jb = lane & 7, j0 = jb * 8;
    const int i = rg * 8 + ri;
    const int b = bh >> 4, h = bh & 15;
    const float* pb = pk + (size_t)bh * Tt * PACKW;
    float* ob = o + (size_t)b * Tt * Cc + h * 64 + i;
    float S[8];
#pragma unroll
    for (int e = 0; e < 8; e++) S[e] = 0.f;

    Frag fa = loadfrag(pb + 0 * PACKW, j0, i);
    Frag fb = loadfrag(pb + 1 * PACKW, j0, i);
    for (int t = 0; t < Tt; t += 2) {
        stepf(S, fa, jb, ob + (size_t)t * Cc);
        int ta = t + 2 < Tt ? t + 2 : Tt - 1;
        fa = loadfrag(pb + (size_t)ta * PACKW, j0, i);
        stepf(S, fb, jb, ob + (size_t)(t + 1) * Cc);
        int tb = t + 3 < Tt ? t + 3 : Tt - 1;
        fb = loadfrag(pb + (size_t)tb * PACKW, j0, i);
    }
}

// ---------------------------------------------------------------------------
// post: GroupNorm + rkv + rosa gate + *g, in-place on o. One block per (b,t).
// ---------------------------------------------------------------------------
__global__ __launch_bounds__(256) void post_k(
    float* __restrict__ o, const float* __restrict__ pk, const float* __restrict__ gbuf,
    const float* __restrict__ r_k, const float* __restrict__ ln_w, const float* __restrict__ ln_b,
    const int* __restrict__ ids, const float* __restrict__ emb, const float* __restrict__ rgate)
{
    __shared__ float sred[4];
    const int bt = blockIdx.x;
    const int b = bt >> 10, t = bt & 1023;
    const int tid = threadIdx.x;
    const int c0 = tid * 4;
    const int h = tid >> 4;
    const int nn = c0 & 63;

    float4 o4 = *(const float4*)(o + (size_t)bt * Cc + c0);
    float s = o4.x + o4.y + o4.z + o4.w;
    float ss = o4.x * o4.x + o4.y * o4.y + o4.z * o4.z + o4.w * o4.w;
#pragma unroll
    for (int m = 1; m < 16; m <<= 1) { s += __shfl_xor(s, m); ss += __shfl_xor(ss, m); }
    float mu = s * (1.f / 64.f);
    float inv = rsqrtf(ss * (1.f / 64.f) - mu * mu + 0.00064f);

    size_t pbase = ((size_t)(b * Hh + h) * Tt + t) * PACKW;
    float4 r4 = *(const float4*)(pk + pbase + SL_R * 64 + nn);
    float4 k4 = *(const float4*)(pk + pbase + SL_K * 64 + nn);
    float4 v4 = *(const float4*)(pk + pbase + SL_V * 64 + nn);
    float4 q4 = *(const float4*)(r_k + h * 64 + nn);
    float dot = r4.x * k4.x * q4.x + r4.y * k4.y * q4.y + r4.z * k4.z * q4.z + r4.w * k4.w * q4.w;
#pragma unroll
    for (int m = 1; m < 16; m <<= 1) dot += __shfl_xor(dot, m);

    float4 lw = *(const float4*)(ln_w + c0);
    float4 lb = *(const float4*)(ln_b + c0);
    float e0 = (o4.x - mu) * inv * lw.x + lb.x + dot * v4.x;
    float e1 = (o4.y - mu) * inv * lw.y + lb.y + dot * v4.y;
    float e2 = (o4.z - mu) * inv * lw.z + lb.z + dot * v4.z;
    float e3 = (o4.w - mu) * inv * lw.w + lb.w + dot * v4.w;

    float4 rg4 = *(const float4*)(rgate + c0);
    float gp = sigf(e0 * rg4.x) + sigf(e1 * rg4.y) + sigf(e2 * rg4.z) + sigf(e3 * rg4.w);
#pragma unroll
    for (int m = 1; m < 64; m <<= 1) gp += __shfl_xor(gp, m);
    if ((tid & 63) == 0) sred[tid >> 6] = gp;
    __syncthreads();
    float gate = (sred[0] + sred[1] + sred[2] + sred[3]) * (1.f / 1024.f);

    const int id = ids[bt];
    float4 em = *(const float4*)(emb + (size_t)id * Cc + c0);
    float4 g4 = *(const float4*)(gbuf + (size_t)bt * Cc + c0);
    float f0 = (e0 * (1.f - gate) + em.x * gate) * g4.x;
    float f1 = (e1 * (1.f - gate) + em.y * gate) * g4.y;
    float f2 = (e2 * (1.f - gate) + em.z * gate) * g4.z;
    float f3 = (e3 * (1.f - gate) + em.w * gate) * g4.w;
    *(float4*)(o + (size_t)bt * Cc + c0) = make_float4(f0, f1, f2, f3);
}

// ---------------------------------------------------------------------------
extern "C" void kernel_launch(void* const* d_in, const int* in_sizes, int n_in,
                              void* d_out, int out_size, void* d_ws, size_t ws_size,
                              hipStream_t stream)
{
    (void)in_sizes; (void)n_in; (void)out_size; (void)ws_size;
    const float* x    = (const float*)d_in[0];
    const int*   ids  = (const int*)d_in[1];
    const float* x_r  = (const float*)d_in[2];
    const float* x_w  = (const float*)d_in[3];
    const float* x_k  = (const float*)d_in[4];
    const float* x_v  = (const float*)d_in[5];
    const float* x_a  = (const float*)d_in[6];
    const float* x_g  = (const float*)d_in[7];
    const float* w0   = (const float*)d_in[8];
    const float* a0   = (const float*)d_in[9];
    const float* w1   = (const float*)d_in[11];
    const float* w2   = (const float*)d_in[12];
    const float* a1   = (const float*)d_in[13];
    const float* a2   = (const float*)d_in[14];
    const float* g1   = (const float*)d_in[17];
    const float* g2   = (const float*)d_in[18];
    const float* k_k  = (const float*)d_in[19];
    const float* k_a  = (const float*)d_in[20];
    const float* r_k  = (const float*)d_in[21];
    const float* Wr   = (const float*)d_in[22];
    const float* Wk   = (const float*)d_in[23];
    const float* Wv   = (const float*)d_in[24];
    const float* Wo   = (const float*)d_in[25];
    const float* ln_w = (const float*)d_in[26];
    const float* ln_b = (const float*)d_in[27];
    const float* emb  = (const float*)d_in[28];
    const float* rg   = (const float*)d_in[29];

    float* ws = (float*)d_ws;
    float* pack = ws;                                          // B*H*T*384 = 12.58M f
    float* obuf = pack + (size_t)Bb * Hh * Tt * PACKW;         // 2M f
    float* gbuf = obuf + (size_t)Mtot * Cc;                    // 2M f
    float* hw = gbuf + (size_t)Mtot * Cc;                      // 2048*64
    float* ha = hw + (size_t)Mtot * 64;                        // 2048*64
    float* hg = ha + (size_t)Mtot * 64;                        // 2048*128

    dim3 blk(256);
    dim3 gbig(Cc / 128, Mtot / 64);

    // r, k, v full projections (mix fused) -> pack slots
    gemm_k<64, 128, 8, 4, 8, 1, 0, 0, 1><<<gbig, blk, 0, stream>>>(x, Wr, x_r, nullptr, pack, Mtot, Cc, Cc, SL_R);
    gemm_k<64, 128, 8, 4, 8, 1, 0, 0, 1><<<gbig, blk, 0, stream>>>(x, Wk, x_k, nullptr, pack, Mtot, Cc, Cc, SL_K);
    gemm_k<64, 128, 8, 4, 8, 1, 0, 0, 1><<<gbig, blk, 0, stream>>>(x, Wv, x_v, nullptr, pack, Mtot, Cc, Cc, SL_V);
    // w = exp(-exp(w0 + tanh(xw@w1)@w2)) -> SL_W
    gemm_k<64, 64, 16, 4, 4, 1, 0, 1, 0><<<dim3(1, 32), blk, 0, stream>>>(x, w1, x_w, nullptr, hw, Mtot, 64, Cc, 0);
    gemm_k<64, 64, 16, 4, 4, 0, 1, 3, 1><<<dim3(16, 32), blk, 0, stream>>>(hw, w2, nullptr, w0, pack, Mtot, Cc, 64, SL_W);
    // a = sigmoid(a0 + (xa@a1)@a2) -> SL_BV (temp, prep converts to kk*a)
    gemm_k<64, 64, 16, 4, 4, 1, 0, 0, 0><<<dim3(1, 32), blk, 0, stream>>>(x, a1, x_a, nullptr, ha, Mtot, 64, Cc, 0);
    gemm_k<64, 64, 16, 4, 4, 0, 1, 2, 1><<<dim3(16, 32), blk, 0, stream>>>(ha, a2, nullptr, a0, pack, Mtot, Cc, 64, SL_BV);
    // g = sigmoid(xg@g1)@g2 -> gbuf
    gemm_k<64, 64, 16, 4, 4, 1, 0, 2, 0><<<dim3(2, 32), blk, 0, stream>>>(x, g1, x_g, nullptr, hg, Mtot, 128, Cc, 0);
    gemm_k<64, 64, 16, 4, 4, 0, 0, 0, 0><<<dim3(16, 32), blk, 0, stream>>>(hg, g2, nullptr, nullptr, gbuf, Mtot, Cc, 128, 0);
    // kk normalize, kmod, -kk, kk*a
    prep_k<<<dim3(Bb * Tt * Hh / 4), blk, 0, stream>>>(pack, k_k, k_a);
    // sequential state scan
    wkv_k<<<dim3(64), blk, 0, stream>>>(pack, obuf);
    // groupnorm + rkv + rosa gate + *g (in-place obuf)
    post_k<<<dim3(Mtot), blk, 0, stream>>>(obuf, pack, gbuf, r_k, ln_w, ln_b, ids, emb, rg);
    // final projection
    gemm_k<64, 128, 8, 4, 8, 0, 0, 0, 0><<<gbig, blk, 0, stream>>>(obuf, Wo, nullptr, nullptr, (float*)d_out, Mtot, Cc, Cc, 0);
}

// Round 3
// 813.243 us; speedup vs baseline: 1.6253x; 1.6253x over previous
//
#include <hip/hip_runtime.h>
#include <hip/hip_bf16.h>
#include <math.h>

// RWKV-7 Tmix: B=2, T=1024, C=1024, H=16, N=64
constexpr int Bb = 2, Tt = 1024, Cc = 1024, Hh = 16, Nn = 64;
constexpr int Mtot = Bb * Tt;          // 2048 rows
constexpr int PACKW = 6 * Nn;          // 384 floats per (b,h,t)
constexpr int SL_R = 0, SL_W = 1, SL_K = 2, SL_V = 3, SL_NK = 4, SL_BV = 5;

__device__ __forceinline__ float sigf(float x) { return 1.f / (1.f + expf(-x)); }

__device__ __forceinline__ unsigned short f2b(float f) {
    unsigned int u = __float_as_uint(f);
    unsigned int r = (u + 0x7FFFu + ((u >> 16) & 1u)) >> 16;
    return (unsigned short)r;
}
__device__ __forceinline__ float b2f(unsigned short h) {
    return __uint_as_float((unsigned int)h << 16);
}

// ===========================================================================
// f32 tiled GEMM (low-rank chains only)
// ===========================================================================
template <int BM, int BN, int BK, int TM, int TN, int MIX, int BIAS, int EPI, int OUTM>
__global__ __launch_bounds__((BM / TM) * (BN / TN)) void gemm_k(
    const float* __restrict__ A, const float* __restrict__ W,
    const float* __restrict__ mixv, const float* __restrict__ bias,
    float* __restrict__ out, int M, int Ncol, int K, int slot)
{
    constexpr int NT = (BM / TM) * (BN / TN);
    constexpr int A4 = BM * BK / 4;
    constexpr int B4 = BK * BN / 4;
    __shared__ float As[BK][BM + 4];
    __shared__ float Bs[BK][BN];
    const int tid = threadIdx.x;
    const int bm = blockIdx.y * BM;
    const int bn = blockIdx.x * BN;
    const int tx = tid % (BN / TN);
    const int ty = tid / (BN / TN);

    float acc[TM][TN];
#pragma unroll
    for (int i = 0; i < TM; i++)
#pragma unroll
        for (int j = 0; j < TN; j++) acc[i][j] = 0.f;

    for (int k0 = 0; k0 < K; k0 += BK) {
        for (int i = tid; i < A4; i += NT) {
            int row = i / (BK / 4), kq = i % (BK / 4);
            int m = bm + row, kb = k0 + kq * 4;
            float4 xv = *(const float4*)(A + (size_t)m * K + kb);
            if (MIX) {
                int t = m & (Tt - 1);
                float4 xp = make_float4(0.f, 0.f, 0.f, 0.f);
                if (t) xp = *(const float4*)(A + (size_t)(m - 1) * K + kb);
                float4 mv = *(const float4*)(mixv + kb);
                xv.x += (xp.x - xv.x) * mv.x;
                xv.y += (xp.y - xv.y) * mv.y;
                xv.z += (xp.z - xv.z) * mv.z;
                xv.w += (xp.w - xv.w) * mv.w;
            }
            As[kq * 4 + 0][row] = xv.x;
            As[kq * 4 + 1][row] = xv.y;
            As[kq * 4 + 2][row] = xv.z;
            As[kq * 4 + 3][row] = xv.w;
        }
        for (int i = tid; i < B4; i += NT) {
            int kr = i / (BN / 4), nq = i % (BN / 4);
            float4 wv = *(const float4*)(W + (size_t)(k0 + kr) * Ncol + bn + nq * 4);
            *(float4*)&Bs[kr][nq * 4] = wv;
        }
        __syncthreads();
#pragma unroll
        for (int kk = 0; kk < BK; kk++) {
            float av[TM], bv[TN];
#pragma unroll
            for (int i = 0; i < TM; i += 4) {
                float4 t4 = *(const float4*)&As[kk][ty * TM + i];
                av[i] = t4.x; av[i + 1] = t4.y; av[i + 2] = t4.z; av[i + 3] = t4.w;
            }
#pragma unroll
            for (int j = 0; j < TN; j += 4) {
                float4 t4 = *(const float4*)&Bs[kk][tx * TN + j];
                bv[j] = t4.x; bv[j + 1] = t4.y; bv[j + 2] = t4.z; bv[j + 3] = t4.w;
            }
#pragma unroll
            for (int i = 0; i < TM; i++)
#pragma unroll
                for (int j = 0; j < TN; j++) acc[i][j] += av[i] * bv[j];
        }
        __syncthreads();
    }

#pragma unroll
    for (int i = 0; i < TM; i++) {
        int m = bm + ty * TM + i;
#pragma unroll
        for (int j = 0; j < TN; j++) {
            int n = bn + tx * TN + j;
            float c = acc[i][j];
            if (BIAS) c += bias[n];
            if (EPI == 1) c = tanhf(c);
            else if (EPI == 2) c = sigf(c);
            else if (EPI == 3) c = expf(-expf(c));
            if (OUTM == 0) {
                out[(size_t)m * Ncol + n] = c;
            } else {
                int b = m >> 10, t = m & (Tt - 1);
                int h = n >> 6, nn2 = n & 63;
                out[((size_t)(b * Hh + h) * Tt + t) * PACKW + slot * Nn + nn2] = c;
            }
        }
    }
}

// ===========================================================================
// mix + split-cast to bf16 hi/lo: xr, xk, xv  [2048][1024]
// ===========================================================================
__global__ __launch_bounds__(256) void mixcast_k(
    const float* __restrict__ x, const float* __restrict__ mr,
    const float* __restrict__ mk, const float* __restrict__ mv,
    unsigned short* __restrict__ xrh, unsigned short* __restrict__ xrl,
    unsigned short* __restrict__ xkh, unsigned short* __restrict__ xkl,
    unsigned short* __restrict__ xvh, unsigned short* __restrict__ xvl)
{
    int idx = (blockIdx.x * 256 + threadIdx.x) * 4;
    int m = idx >> 10, c = idx & 1023;
    int t = m & (Tt - 1);
    float4 xc = *(const float4*)(x + idx);
    float4 xp = make_float4(0.f, 0.f, 0.f, 0.f);
    if (t) xp = *(const float4*)(x + idx - Cc);
    float4 d = make_float4(xp.x - xc.x, xp.y - xc.y, xp.z - xc.z, xp.w - xc.w);
    float val[4];
    float4 m4;
    ushort4 h4, l4;
#define EMIT(mixp, dsth, dstl)                                         \
    m4 = *(const float4*)(mixp + c);                                   \
    val[0] = xc.x + d.x * m4.x; val[1] = xc.y + d.y * m4.y;            \
    val[2] = xc.z + d.z * m4.z; val[3] = xc.w + d.w * m4.w;            \
    h4.x = f2b(val[0]); l4.x = f2b(val[0] - b2f(h4.x));                \
    h4.y = f2b(val[1]); l4.y = f2b(val[1] - b2f(h4.y));                \
    h4.z = f2b(val[2]); l4.z = f2b(val[2] - b2f(h4.z));                \
    h4.w = f2b(val[3]); l4.w = f2b(val[3] - b2f(h4.w));                \
    *(ushort4*)(dsth + idx) = h4; *(ushort4*)(dstl + idx) = l4;
    EMIT(mr, xrh, xrl)
    EMIT(mk, xkh, xkl)
    EMIT(mv, xvh, xvl)
#undef EMIT
}

// ===========================================================================
// weight transpose + split-cast: WT[n][k] hi/lo from W[k][n] f32. 64x64 tiles.
// ===========================================================================
__global__ __launch_bounds__(256) void wtrans_k(
    const float* __restrict__ W0, const float* __restrict__ W1,
    const float* __restrict__ W2, const float* __restrict__ W3,
    unsigned short* __restrict__ WTh, unsigned short* __restrict__ WTl)
{
    __shared__ float ls[64][65];
    const int z = blockIdx.z;
    const float* W = (z == 0) ? W0 : (z == 1) ? W1 : (z == 2) ? W2 : W3;
    unsigned short* dsth = WTh + (size_t)z * Cc * Cc;
    unsigned short* dstl = WTl + (size_t)z * Cc * Cc;
    const int k0 = blockIdx.x * 64, n0 = blockIdx.y * 64;
    const int tid = threadIdx.x;
    const int rr = tid >> 4, c4 = tid & 15;
#pragma unroll
    for (int q = 0; q < 4; q++) {
        int kr = rr + q * 16;
        float4 v = *(const float4*)(W + (size_t)(k0 + kr) * Cc + n0 + c4 * 4);
        ls[kr][c4 * 4 + 0] = v.x; ls[kr][c4 * 4 + 1] = v.y;
        ls[kr][c4 * 4 + 2] = v.z; ls[kr][c4 * 4 + 3] = v.w;
    }
    __syncthreads();
#pragma unroll
    for (int q = 0; q < 4; q++) {
        int nr = rr + q * 16;
        ushort4 h, l;
        float v0 = ls[c4 * 4 + 0][nr], v1 = ls[c4 * 4 + 1][nr];
        float v2 = ls[c4 * 4 + 2][nr], v3 = ls[c4 * 4 + 3][nr];
        h.x = f2b(v0); l.x = f2b(v0 - b2f(h.x));
        h.y = f2b(v1); l.y = f2b(v1 - b2f(h.y));
        h.z = f2b(v2); l.z = f2b(v2 - b2f(h.z));
        h.w = f2b(v3); l.w = f2b(v3 - b2f(h.w));
        *(ushort4*)(dsth + (size_t)(n0 + nr) * Cc + k0 + c4 * 4) = h;
        *(ushort4*)(dstl + (size_t)(n0 + nr) * Cc + k0 + c4 * 4) = l;
    }
}

// ===========================================================================
// split bf16 MFMA GEMM (3-term: hh + hl + lh), f32-quality.
// out[M,N] = A[M,K] @ BT[N,K]^T. 128x64 tile, 4 waves, grid fills 256 CUs.
// ===========================================================================
typedef short short8 __attribute__((ext_vector_type(8)));
typedef float f32x4 __attribute__((ext_vector_type(4)));

template <int OUTM>
__global__ __launch_bounds__(256) void mgemm3_k(
    const unsigned short* __restrict__ Ahi, const unsigned short* __restrict__ Alo,
    const unsigned short* __restrict__ Bhi, const unsigned short* __restrict__ Blo,
    float* __restrict__ out, int M, int Ncol, int K, int slot)
{
    __shared__ unsigned short Ash[128][40];
    __shared__ unsigned short Asl[128][40];
    __shared__ unsigned short Bsh[64][40];
    __shared__ unsigned short Bsl[64][40];
    const int tid = threadIdx.x;
    const int lane = tid & 63, wid = tid >> 6;
    const int wr = wid >> 1, wc = wid & 1;
    const int bm = blockIdx.y * 128, bn = blockIdx.x * 64;
    const int l15 = lane & 15, lk = lane >> 4;
    const int srow = tid >> 2, skc = tid & 3;

    f32x4 acc[4][2];
#pragma unroll
    for (int i = 0; i < 4; i++)
#pragma unroll
        for (int j = 0; j < 2; j++) acc[i][j] = (f32x4){0.f, 0.f, 0.f, 0.f};

    for (int k0 = 0; k0 < K; k0 += 32) {
        const size_t aoff = (size_t)(bm + srow) * K + k0 + skc * 8;
        uint4 ah0 = *(const uint4*)(Ahi + aoff);
        uint4 ah1 = *(const uint4*)(Ahi + aoff + (size_t)64 * K);
        uint4 al0 = *(const uint4*)(Alo + aoff);
        uint4 al1 = *(const uint4*)(Alo + aoff + (size_t)64 * K);
        const size_t boff = (size_t)(bn + srow) * K + k0 + skc * 8;
        uint4 bh0 = *(const uint4*)(Bhi + boff);
        uint4 bl0 = *(const uint4*)(Blo + boff);
        *(uint4*)&Ash[srow][skc * 8] = ah0;
        *(uint4*)&Ash[srow + 64][skc * 8] = ah1;
        *(uint4*)&Asl[srow][skc * 8] = al0;
        *(uint4*)&Asl[srow + 64][skc * 8] = al1;
        *(uint4*)&Bsh[srow][skc * 8] = bh0;
        *(uint4*)&Bsl[srow][skc * 8] = bl0;
        __syncthreads();
        short8 afh[4], afl[4], bfh[2], bfl[2];
#pragma unroll
        for (int m = 0; m < 4; m++) {
            afh[m] = *(const short8*)&Ash[wr * 64 + m * 16 + l15][lk * 8];
            afl[m] = *(const short8*)&Asl[wr * 64 + m * 16 + l15][lk * 8];
        }
#pragma unroll
        for (int n = 0; n < 2; n++) {
            bfh[n] = *(const short8*)&Bsh[wc * 32 + n * 16 + l15][lk * 8];
            bfl[n] = *(const short8*)&Bsl[wc * 32 + n * 16 + l15][lk * 8];
        }
#pragma unroll
        for (int m = 0; m < 4; m++)
#pragma unroll
            for (int n = 0; n < 2; n++) {
                acc[m][n] = __builtin_amdgcn_mfma_f32_16x16x32_bf16(afh[m], bfh[n], acc[m][n], 0, 0, 0);
                acc[m][n] = __builtin_amdgcn_mfma_f32_16x16x32_bf16(afh[m], bfl[n], acc[m][n], 0, 0, 0);
                acc[m][n] = __builtin_amdgcn_mfma_f32_16x16x32_bf16(afl[m], bfh[n], acc[m][n], 0, 0, 0);
            }
        __syncthreads();
    }

#pragma unroll
    for (int m = 0; m < 4; m++) {
#pragma unroll
        for (int n = 0; n < 2; n++) {
            int col = bn + wc * 32 + n * 16 + l15;
#pragma unroll
            for (int r = 0; r < 4; r++) {
                int row = bm + wr * 64 + m * 16 + lk * 4 + r;
                float cval = acc[m][n][r];
                if (OUTM == 0) {
                    out[(size_t)row * Ncol + col] = cval;
                } else {
                    int b = row >> 10, t = row & (Tt - 1);
                    int h = col >> 6, nn2 = col & 63;
                    out[((size_t)(b * Hh + h) * Tt + t) * PACKW + slot * Nn + nn2] = cval;
                }
            }
        }
    }
}

// ===========================================================================
// prep: kk normalize etc
// ===========================================================================
__global__ __launch_bounds__(256) void prep_k(float* __restrict__ pk,
                                              const float* __restrict__ k_k,
                                              const float* __restrict__ k_a)
{
    int inst = blockIdx.x * 4 + (threadIdx.x >> 6);
    int lane = threadIdx.x & 63;
    int b = inst >> 14;
    int rem = inst & 16383;
    int t = rem >> 4;
    int h = rem & 15;
    size_t base = ((size_t)(b * Hh + h) * Tt + t) * PACKW;
    int c = h * 64 + lane;
    float kraw = pk[base + SL_K * 64 + lane];
    float a = pk[base + SL_BV * 64 + lane];
    float kkv = kraw * k_k[c];
    float ss = kkv * kkv;
#pragma unroll
    for (int m = 1; m < 64; m <<= 1) ss += __shfl_xor(ss, m);
    float kkn = kkv / fmaxf(sqrtf(ss), 1e-12f);
    pk[base + SL_NK * 64 + lane] = -kkn;
    pk[base + SL_BV * 64 + lane] = kkn * a;
    pk[base + SL_K * 64 + lane] = kraw * (1.f + (a - 1.f) * k_a[c]);
}

// ===========================================================================
// WKV scan v2: 256 single-wave blocks; 16-step LDS ring via global_load_lds
// with counted vmcnt; DPP reductions.
// ===========================================================================
constexpr int WD = 16;

typedef __attribute__((address_space(1))) const void GV;
typedef __attribute__((address_space(3))) void LV;

__device__ __forceinline__ void gl16(const void* g, void* l) {
    __builtin_amdgcn_global_load_lds((GV*)g, (LV*)l, 16, 0, 0);
}
__device__ __forceinline__ void gl4(const void* g, void* l) {
    __builtin_amdgcn_global_load_lds((GV*)g, (LV*)l, 4, 0, 0);
}

__device__ __forceinline__ void wkv_issue(const float* gsrc, float* lds, int lane) {
    gl16(gsrc + lane * 4, lds);            // bytes 0..1023   (r,w,k,v)
    gl4(gsrc + 256 + lane, lds + 256);     // nk
    gl4(gsrc + 320 + lane, lds + 320);     // bv
}

#define WAITV asm volatile("s_waitcnt vmcnt(42)" ::: "memory")

template <int C>
__device__ __forceinline__ float dppmov(float x) {
    return __int_as_float(__builtin_amdgcn_mov_dpp(__float_as_int(x), C, 0xF, 0xF, 1));
}
__device__ __forceinline__ float red8(float v) {
    v += dppmov<0xB1>(v);   // quad_perm xor1
    v += dppmov<0x4E>(v);   // quad_perm xor2
    v += dppmov<0x141>(v);  // row_half_mirror
    return v;
}

struct Frag {
    float4 r0, r1, w0, w1, k0, k1, n0, n1, b0, b1;
    float v;
};

__device__ __forceinline__ Frag ldsfrag(const float* s, int j0, int i) {
    Frag f;
    f.r0 = *(const float4*)(s + j0);        f.r1 = *(const float4*)(s + j0 + 4);
    f.w0 = *(const float4*)(s + 64 + j0);   f.w1 = *(const float4*)(s + 64 + j0 + 4);
    f.k0 = *(const float4*)(s + 128 + j0);  f.k1 = *(const float4*)(s + 128 + j0 + 4);
    f.n0 = *(const float4*)(s + 256 + j0);  f.n1 = *(const float4*)(s + 256 + j0 + 4);
    f.b0 = *(const float4*)(s + 320 + j0);  f.b1 = *(const float4*)(s + 320 + j0 + 4);
    f.v = s[192 + i];
    return f;
}

__device__ __forceinline__ float dot8(const float S[8], float4 a, float4 b) {
    float p0 = fmaf(S[1], a.y, S[0] * a.x);
    float p1 = fmaf(S[3], a.w, S[2] * a.z);
    float p2 = fmaf(S[5], b.y, S[4] * b.x);
    float p3 = fmaf(S[7], b.w, S[6] * b.z);
    return (p0 + p1) + (p2 + p3);
}

__device__ __forceinline__ void upd4(float* S, float4 w, float4 bv, float4 km, float sa, float v) {
    S[0] = fmaf(S[0], w.x, fmaf(sa, bv.x, v * km.x));
    S[1] = fmaf(S[1], w.y, fmaf(sa, bv.y, v * km.y));
    S[2] = fmaf(S[2], w.z, fmaf(sa, bv.z, v * km.z));
    S[3] = fmaf(S[3], w.w, fmaf(sa, bv.w, v * km.w));
}

__device__ __forceinline__ void stepf(float S[8], const Frag& f, int jb, float* optr) {
    float sa = dot8(S, f.n0, f.n1);
    sa = red8(sa);
    upd4(S, f.w0, f.b0, f.k0, sa, f.v);
    upd4(S + 4, f.w1, f.b1, f.k1, sa, f.v);
    float ot = dot8(S, f.r0, f.r1);
    ot = red8(ot);
    if (jb == 0) *optr = ot;
}

__global__ __launch_bounds__(64) void wkv_k(const float* __restrict__ pk, float* __restrict__ o)
{
    __shared__ __attribute__((aligned(16))) float ring[WD][PACKW];
    const int gw = blockIdx.x;              // 0..255
    const int bh = gw >> 3, rg = gw & 7;
    const int lane = threadIdx.x;
    const int ri = lane >> 3, jb = lane & 7, j0 = jb * 8;
    const int i = rg * 8 + ri;
    const int b = bh >> 4, h = bh & 15;
    const float* pb = pk + (size_t)bh * Tt * PACKW;
    float* ob = o + (size_t)b * Tt * Cc + h * 64 + i;

    float S[8];
#pragma unroll
    for (int e = 0; e < 8; e++) S[e] = 0.f;

    for (int d = 0; d < WD; d++) wkv_issue(pb + (size_t)d * PACKW, ring[d], lane);
    WAITV;

    Frag fa = ldsfrag(ring[0], j0, i);
    for (int t = 0; t < Tt; t += 2) {
        Frag fb = ldsfrag(ring[(t + 1) & (WD - 1)], j0, i);
        stepf(S, fa, jb, ob + (size_t)t * Cc);
        int ta = t + WD < Tt ? t + WD : Tt - 1;
        wkv_issue(pb + (size_t)ta * PACKW, ring[t & (WD - 1)], lane);
        WAITV;
        Frag fc = ldsfrag(ring[(t + 2) & (WD - 1)], j0, i);
        stepf(S, fb, jb, ob + (size_t)(t + 1) * Cc);
        int tb = t + 1 + WD < Tt ? t + 1 + WD : Tt - 1;
        wkv_issue(pb + (size_t)tb * PACKW, ring[(t + 1) & (WD - 1)], lane);
        WAITV;
        fa = fc;
    }
}

// ===========================================================================
// post: GroupNorm + rkv + rosa gate + *g -> split bf16 activation
// ===========================================================================
__global__ __launch_bounds__(256) void post_k(
    const float* __restrict__ o, const float* __restrict__ pk, const float* __restrict__ gbuf,
    const float* __restrict__ r_k, const float* __restrict__ ln_w, const float* __restrict__ ln_b,
    const int* __restrict__ ids, const float* __restrict__ emb, const float* __restrict__ rgate,
    unsigned short* __restrict__ outh, unsigned short* __restrict__ outl)
{
    __shared__ float sred[4];
    const int bt = blockIdx.x;
    const int b = bt >> 10, t = bt & 1023;
    const int tid = threadIdx.x;
    const int c0 = tid * 4;
    const int h = tid >> 4;
    const int nn = c0 & 63;

    float4 o4 = *(const float4*)(o + (size_t)bt * Cc + c0);
    float s = o4.x + o4.y + o4.z + o4.w;
    float ss = o4.x * o4.x + o4.y * o4.y + o4.z * o4.z + o4.w * o4.w;
#pragma unroll
    for (int m = 1; m < 16; m <<= 1) { s += __shfl_xor(s, m); ss += __shfl_xor(ss, m); }
    float mu = s * (1.f / 64.f);
    float inv = rsqrtf(ss * (1.f / 64.f) - mu * mu + 0.00064f);

    size_t pbase = ((size_t)(b * Hh + h) * Tt + t) * PACKW;
    float4 r4 = *(const float4*)(pk + pbase + SL_R * 64 + nn);
    float4 k4 = *(const float4*)(pk + pbase + SL_K * 64 + nn);
    float4 v4 = *(const float4*)(pk + pbase + SL_V * 64 + nn);
    float4 q4 = *(const float4*)(r_k + h * 64 + nn);
    float dot = r4.x * k4.x * q4.x + r4.y * k4.y * q4.y + r4.z * k4.z * q4.z + r4.w * k4.w * q4.w;
#pragma unroll
    for (int m = 1; m < 16; m <<= 1) dot += __shfl_xor(dot, m);

    float4 lw = *(const float4*)(ln_w + c0);
    float4 lb = *(const float4*)(ln_b + c0);
    float e0 = (o4.x - mu) * inv * lw.x + lb.x + dot * v4.x;
    float e1 = (o4.y - mu) * inv * lw.y + lb.y + dot * v4.y;
    float e2 = (o4.z - mu) * inv * lw.z + lb.z + dot * v4.z;
    float e3 = (o4.w - mu) * inv * lw.w + lb.w + dot * v4.w;

    float4 rg4 = *(const float4*)(rgate + c0);
    float gp = sigf(e0 * rg4.x) + sigf(e1 * rg4.y) + sigf(e2 * rg4.z) + sigf(e3 * rg4.w);
#pragma unroll
    for (int m = 1; m < 64; m <<= 1) gp += __shfl_xor(gp, m);
    if ((tid & 63) == 0) sred[tid >> 6] = gp;
    __syncthreads();
    float gate = (sred[0] + sred[1] + sred[2] + sred[3]) * (1.f / 1024.f);

    const int id = ids[bt];
    float4 em = *(const float4*)(emb + (size_t)id * Cc + c0);
    float4 g4 = *(const float4*)(gbuf + (size_t)bt * Cc + c0);
    float f0 = (e0 * (1.f - gate) + em.x * gate) * g4.x;
    float f1 = (e1 * (1.f - gate) + em.y * gate) * g4.y;
    float f2 = (e2 * (1.f - gate) + em.z * gate) * g4.z;
    float f3 = (e3 * (1.f - gate) + em.w * gate) * g4.w;
    ushort4 h4, l4;
    h4.x = f2b(f0); l4.x = f2b(f0 - b2f(h4.x));
    h4.y = f2b(f1); l4.y = f2b(f1 - b2f(h4.y));
    h4.z = f2b(f2); l4.z = f2b(f2 - b2f(h4.z));
    h4.w = f2b(f3); l4.w = f2b(f3 - b2f(h4.w));
    *(ushort4*)(outh + (size_t)bt * Cc + c0) = h4;
    *(ushort4*)(outl + (size_t)bt * Cc + c0) = l4;
}

// ===========================================================================
extern "C" void kernel_launch(void* const* d_in, const int* in_sizes, int n_in,
                              void* d_out, int out_size, void* d_ws, size_t ws_size,
                              hipStream_t stream)
{
    (void)in_sizes; (void)n_in; (void)out_size; (void)ws_size;
    const float* x    = (const float*)d_in[0];
    const int*   ids  = (const int*)d_in[1];
    const float* x_r  = (const float*)d_in[2];
    const float* x_w  = (const float*)d_in[3];
    const float* x_k  = (const float*)d_in[4];
    const float* x_v  = (const float*)d_in[5];
    const float* x_a  = (const float*)d_in[6];
    const float* x_g  = (const float*)d_in[7];
    const float* w0   = (const float*)d_in[8];
    const float* a0   = (const float*)d_in[9];
    const float* w1   = (const float*)d_in[11];
    const float* w2   = (const float*)d_in[12];
    const float* a1   = (const float*)d_in[13];
    const float* a2   = (const float*)d_in[14];
    const float* g1   = (const float*)d_in[17];
    const float* g2   = (const float*)d_in[18];
    const float* k_k  = (const float*)d_in[19];
    const float* k_a  = (const float*)d_in[20];
    const float* r_k  = (const float*)d_in[21];
    const float* Wr   = (const float*)d_in[22];
    const float* Wk   = (const float*)d_in[23];
    const float* Wv   = (const float*)d_in[24];
    const float* Wo   = (const float*)d_in[25];
    const float* ln_w = (const float*)d_in[26];
    const float* ln_b = (const float*)d_in[27];
    const float* emb  = (const float*)d_in[28];
    const float* rg   = (const float*)d_in[29];

    float* ws = (float*)d_ws;
    float* pack = ws;                                          // 12,582,912 f
    float* obuf = pack + (size_t)12582912;                     // 2,097,152 f
    float* gbuf = obuf + (size_t)2097152;                      // 2,097,152 f
    float* hw   = gbuf + (size_t)2097152;                      // 131072
    float* ha   = hw + (size_t)131072;                         // 131072
    float* hg   = ha + (size_t)131072;                         // 262144
    unsigned short* u = (unsigned short*)(hg + (size_t)262144);
    unsigned short* xrh = u;                    // each 2,097,152 ushorts
    unsigned short* xrl = xrh + (size_t)2097152;
    unsigned short* xkh = xrl + (size_t)2097152;
    unsigned short* xkl = xkh + (size_t)2097152;
    unsigned short* xvh = xkl + (size_t)2097152;
    unsigned short* xvl = xvh + (size_t)2097152;
    unsigned short* wth = xvl + (size_t)2097152;   // 4 x 1,048,576
    unsigned short* wtl = wth + (size_t)4194304;   // 4 x 1,048,576
    // obufb hi/lo alias xr (dead after the R projection)
    unsigned short* obh = xrh;
    unsigned short* obl = xrl;

    dim3 blk(256);

    wtrans_k<<<dim3(16, 16, 4), blk, 0, stream>>>(Wr, Wk, Wv, Wo, wth, wtl);
    mixcast_k<<<dim3(2048), blk, 0, stream>>>(x, x_r, x_k, x_v, xrh, xrl, xkh, xkl, xvh, xvl);

    // r, k, v projections via split bf16 MFMA -> pack slots (f32 quality)
    dim3 gmm(Cc / 64, Mtot / 128);   // (16,16) = 256 blocks
    mgemm3_k<1><<<gmm, blk, 0, stream>>>(xrh, xrl, wth + (size_t)0 * 1048576, wtl + (size_t)0 * 1048576, pack, Mtot, Cc, Cc, SL_R);
    mgemm3_k<1><<<gmm, blk, 0, stream>>>(xkh, xkl, wth + (size_t)1 * 1048576, wtl + (size_t)1 * 1048576, pack, Mtot, Cc, Cc, SL_K);
    mgemm3_k<1><<<gmm, blk, 0, stream>>>(xvh, xvl, wth + (size_t)2 * 1048576, wtl + (size_t)2 * 1048576, pack, Mtot, Cc, Cc, SL_V);

    // w = exp(-exp(w0 + tanh(xw@w1)@w2)) -> SL_W
    gemm_k<64, 64, 16, 4, 4, 1, 0, 1, 0><<<dim3(1, 32), blk, 0, stream>>>(x, w1, x_w, nullptr, hw, Mtot, 64, Cc, 0);
    gemm_k<64, 64, 16, 4, 4, 0, 1, 3, 1><<<dim3(16, 32), blk, 0, stream>>>(hw, w2, nullptr, w0, pack, Mtot, Cc, 64, SL_W);
    // a = sigmoid(a0 + (xa@a1)@a2) -> SL_BV (temp)
    gemm_k<64, 64, 16, 4, 4, 1, 0, 0, 0><<<dim3(1, 32), blk, 0, stream>>>(x, a1, x_a, nullptr, ha, Mtot, 64, Cc, 0);
    gemm_k<64, 64, 16, 4, 4, 0, 1, 2, 1><<<dim3(16, 32), blk, 0, stream>>>(ha, a2, nullptr, a0, pack, Mtot, Cc, 64, SL_BV);
    // g = sigmoid(xg@g1)@g2 -> gbuf
    gemm_k<64, 64, 16, 4, 4, 1, 0, 2, 0><<<dim3(2, 32), blk, 0, stream>>>(x, g1, x_g, nullptr, hg, Mtot, 128, Cc, 0);
    gemm_k<64, 64, 16, 4, 4, 0, 0, 0, 0><<<dim3(16, 32), blk, 0, stream>>>(hg, g2, nullptr, nullptr, gbuf, Mtot, Cc, 128, 0);

    prep_k<<<dim3(Bb * Tt * Hh / 4), blk, 0, stream>>>(pack, k_k, k_a);
    wkv_k<<<dim3(256), dim3(64), 0, stream>>>(pack, obuf);
    post_k<<<dim3(Mtot), blk, 0, stream>>>(obuf, pack, gbuf, r_k, ln_w, ln_b, ids, emb, rg, obh, obl);
    mgemm3_k<0><<<gmm, blk, 0, stream>>>(obh, obl, wth + (size_t)3 * 1048576, wtl + (size_t)3 * 1048576, (float*)d_out, Mtot, Cc, Cc, 0);
}

// Round 4
// 543.894 us; speedup vs baseline: 2.4301x; 1.4952x over previous
//
#include <hip/hip_runtime.h>
#include <hip/hip_bf16.h>
#include <math.h>

// RWKV-7 Tmix: B=2, T=1024, C=1024, H=16, N=64
constexpr int Bb = 2, Tt = 1024, Cc = 1024, Hh = 16, Nn = 64;
constexpr int Mtot = Bb * Tt;          // 2048 rows
constexpr int PACKW = 6 * Nn;          // 384 floats per (b,h,t)
constexpr int SL_R = 0, SL_W = 1, SL_K = 2, SL_V = 3, SL_NK = 4, SL_BV = 5;

__device__ __forceinline__ float sigf(float x) { return 1.f / (1.f + expf(-x)); }

__device__ __forceinline__ unsigned short f2b(float f) {
    unsigned int u = __float_as_uint(f);
    unsigned int r = (u + 0x7FFFu + ((u >> 16) & 1u)) >> 16;
    return (unsigned short)r;
}
__device__ __forceinline__ float b2f(unsigned short h) {
    return __uint_as_float((unsigned int)h << 16);
}

// ===========================================================================
// f32 tiled GEMM (low-rank chains only)
// ===========================================================================
template <int BM, int BN, int BK, int TM, int TN, int MIX, int BIAS, int EPI, int OUTM>
__global__ __launch_bounds__((BM / TM) * (BN / TN)) void gemm_k(
    const float* __restrict__ A, const float* __restrict__ W,
    const float* __restrict__ mixv, const float* __restrict__ bias,
    float* __restrict__ out, int M, int Ncol, int K, int slot)
{
    constexpr int NT = (BM / TM) * (BN / TN);
    constexpr int A4 = BM * BK / 4;
    constexpr int B4 = BK * BN / 4;
    __shared__ float As[BK][BM + 4];
    __shared__ float Bs[BK][BN];
    const int tid = threadIdx.x;
    const int bm = blockIdx.y * BM;
    const int bn = blockIdx.x * BN;
    const int tx = tid % (BN / TN);
    const int ty = tid / (BN / TN);

    float acc[TM][TN];
#pragma unroll
    for (int i = 0; i < TM; i++)
#pragma unroll
        for (int j = 0; j < TN; j++) acc[i][j] = 0.f;

    for (int k0 = 0; k0 < K; k0 += BK) {
        for (int i = tid; i < A4; i += NT) {
            int row = i / (BK / 4), kq = i % (BK / 4);
            int m = bm + row, kb = k0 + kq * 4;
            float4 xv = *(const float4*)(A + (size_t)m * K + kb);
            if (MIX) {
                int t = m & (Tt - 1);
                float4 xp = make_float4(0.f, 0.f, 0.f, 0.f);
                if (t) xp = *(const float4*)(A + (size_t)(m - 1) * K + kb);
                float4 mv = *(const float4*)(mixv + kb);
                xv.x += (xp.x - xv.x) * mv.x;
                xv.y += (xp.y - xv.y) * mv.y;
                xv.z += (xp.z - xv.z) * mv.z;
                xv.w += (xp.w - xv.w) * mv.w;
            }
            As[kq * 4 + 0][row] = xv.x;
            As[kq * 4 + 1][row] = xv.y;
            As[kq * 4 + 2][row] = xv.z;
            As[kq * 4 + 3][row] = xv.w;
        }
        for (int i = tid; i < B4; i += NT) {
            int kr = i / (BN / 4), nq = i % (BN / 4);
            float4 wv = *(const float4*)(W + (size_t)(k0 + kr) * Ncol + bn + nq * 4);
            *(float4*)&Bs[kr][nq * 4] = wv;
        }
        __syncthreads();
#pragma unroll
        for (int kk = 0; kk < BK; kk++) {
            float av[TM], bv[TN];
#pragma unroll
            for (int i = 0; i < TM; i += 4) {
                float4 t4 = *(const float4*)&As[kk][ty * TM + i];
                av[i] = t4.x; av[i + 1] = t4.y; av[i + 2] = t4.z; av[i + 3] = t4.w;
            }
#pragma unroll
            for (int j = 0; j < TN; j += 4) {
                float4 t4 = *(const float4*)&Bs[kk][tx * TN + j];
                bv[j] = t4.x; bv[j + 1] = t4.y; bv[j + 2] = t4.z; bv[j + 3] = t4.w;
            }
#pragma unroll
            for (int i = 0; i < TM; i++)
#pragma unroll
                for (int j = 0; j < TN; j++) acc[i][j] += av[i] * bv[j];
        }
        __syncthreads();
    }

#pragma unroll
    for (int i = 0; i < TM; i++) {
        int m = bm + ty * TM + i;
#pragma unroll
        for (int j = 0; j < TN; j++) {
            int n = bn + tx * TN + j;
            float c = acc[i][j];
            if (BIAS) c += bias[n];
            if (EPI == 1) c = tanhf(c);
            else if (EPI == 2) c = sigf(c);
            else if (EPI == 3) c = expf(-expf(c));
            if (OUTM == 0) {
                out[(size_t)m * Ncol + n] = c;
            } else {
                int b = m >> 10, t = m & (Tt - 1);
                int h = n >> 6, nn2 = n & 63;
                out[((size_t)(b * Hh + h) * Tt + t) * PACKW + slot * Nn + nn2] = c;
            }
        }
    }
}

// ===========================================================================
// mix + split-cast to bf16 hi/lo: xr, xk, xv  [2048][1024]
// ===========================================================================
__global__ __launch_bounds__(256) void mixcast_k(
    const float* __restrict__ x, const float* __restrict__ mr,
    const float* __restrict__ mk, const float* __restrict__ mv,
    unsigned short* __restrict__ xrh, unsigned short* __restrict__ xrl,
    unsigned short* __restrict__ xkh, unsigned short* __restrict__ xkl,
    unsigned short* __restrict__ xvh, unsigned short* __restrict__ xvl)
{
    int idx = (blockIdx.x * 256 + threadIdx.x) * 4;
    int m = idx >> 10, c = idx & 1023;
    int t = m & (Tt - 1);
    float4 xc = *(const float4*)(x + idx);
    float4 xp = make_float4(0.f, 0.f, 0.f, 0.f);
    if (t) xp = *(const float4*)(x + idx - Cc);
    float4 d = make_float4(xp.x - xc.x, xp.y - xc.y, xp.z - xc.z, xp.w - xc.w);
    float val[4];
    float4 m4;
    ushort4 h4, l4;
#define EMIT(mixp, dsth, dstl)                                         \
    m4 = *(const float4*)(mixp + c);                                   \
    val[0] = xc.x + d.x * m4.x; val[1] = xc.y + d.y * m4.y;            \
    val[2] = xc.z + d.z * m4.z; val[3] = xc.w + d.w * m4.w;            \
    h4.x = f2b(val[0]); l4.x = f2b(val[0] - b2f(h4.x));                \
    h4.y = f2b(val[1]); l4.y = f2b(val[1] - b2f(h4.y));                \
    h4.z = f2b(val[2]); l4.z = f2b(val[2] - b2f(h4.z));                \
    h4.w = f2b(val[3]); l4.w = f2b(val[3] - b2f(h4.w));                \
    *(ushort4*)(dsth + idx) = h4; *(ushort4*)(dstl + idx) = l4;
    EMIT(mr, xrh, xrl)
    EMIT(mk, xkh, xkl)
    EMIT(mv, xvh, xvl)
#undef EMIT
}

// ===========================================================================
// weight transpose + split-cast: WT[n][k] hi/lo from W[k][n] f32. 64x64 tiles.
// ===========================================================================
__global__ __launch_bounds__(256) void wtrans_k(
    const float* __restrict__ W0, const float* __restrict__ W1,
    const float* __restrict__ W2, const float* __restrict__ W3,
    unsigned short* __restrict__ WTh, unsigned short* __restrict__ WTl)
{
    __shared__ float ls[64][65];
    const int z = blockIdx.z;
    const float* W = (z == 0) ? W0 : (z == 1) ? W1 : (z == 2) ? W2 : W3;
    unsigned short* dsth = WTh + (size_t)z * Cc * Cc;
    unsigned short* dstl = WTl + (size_t)z * Cc * Cc;
    const int k0 = blockIdx.x * 64, n0 = blockIdx.y * 64;
    const int tid = threadIdx.x;
    const int rr = tid >> 4, c4 = tid & 15;
#pragma unroll
    for (int q = 0; q < 4; q++) {
        int kr = rr + q * 16;
        float4 v = *(const float4*)(W + (size_t)(k0 + kr) * Cc + n0 + c4 * 4);
        ls[kr][c4 * 4 + 0] = v.x; ls[kr][c4 * 4 + 1] = v.y;
        ls[kr][c4 * 4 + 2] = v.z; ls[kr][c4 * 4 + 3] = v.w;
    }
    __syncthreads();
#pragma unroll
    for (int q = 0; q < 4; q++) {
        int nr = rr + q * 16;
        ushort4 h, l;
        float v0 = ls[c4 * 4 + 0][nr], v1 = ls[c4 * 4 + 1][nr];
        float v2 = ls[c4 * 4 + 2][nr], v3 = ls[c4 * 4 + 3][nr];
        h.x = f2b(v0); l.x = f2b(v0 - b2f(h.x));
        h.y = f2b(v1); l.y = f2b(v1 - b2f(h.y));
        h.z = f2b(v2); l.z = f2b(v2 - b2f(h.z));
        h.w = f2b(v3); l.w = f2b(v3 - b2f(h.w));
        *(ushort4*)(dsth + (size_t)(n0 + nr) * Cc + k0 + c4 * 4) = h;
        *(ushort4*)(dstl + (size_t)(n0 + nr) * Cc + k0 + c4 * 4) = l;
    }
}

// ===========================================================================
// split bf16 MFMA GEMM (3-term: hh + hl + lh), f32-quality.
// 128x64 tile, 4 waves, double-buffered LDS, register-staged prefetch.
// ===========================================================================
typedef short short8 __attribute__((ext_vector_type(8)));
typedef float f32x4 __attribute__((ext_vector_type(4)));
typedef float f32x2 __attribute__((ext_vector_type(2)));

template <int OUTM>
__global__ __launch_bounds__(256) void mgemm3_k(
    const unsigned short* __restrict__ Ahi, const unsigned short* __restrict__ Alo,
    const unsigned short* __restrict__ Bhi, const unsigned short* __restrict__ Blo,
    float* __restrict__ out, int M, int Ncol, int K, int slot)
{
    __shared__ unsigned short Ash[2][128][40];
    __shared__ unsigned short Asl[2][128][40];
    __shared__ unsigned short Bsh[2][64][40];
    __shared__ unsigned short Bsl[2][64][40];
    const int tid = threadIdx.x;
    const int lane = tid & 63, wid = tid >> 6;
    const int wr = wid >> 1, wc = wid & 1;
    const int bm = blockIdx.y * 128, bn = blockIdx.x * 64;
    const int l15 = lane & 15, lk = lane >> 4;
    const int srow = tid >> 2, skc = tid & 3;

    f32x4 acc[4][2];
#pragma unroll
    for (int i = 0; i < 4; i++)
#pragma unroll
        for (int j = 0; j < 2; j++) acc[i][j] = (f32x4){0.f, 0.f, 0.f, 0.f};

    uint4 ra0, ra1, rl0, rl1, rb0, rbl;
    const size_t arow = (size_t)(bm + srow) * K + skc * 8;
    const size_t brow = (size_t)(bn + srow) * K + skc * 8;

#define LOADG(k0)                                                  \
    ra0 = *(const uint4*)(Ahi + arow + (k0));                      \
    ra1 = *(const uint4*)(Ahi + arow + (size_t)64 * K + (k0));     \
    rl0 = *(const uint4*)(Alo + arow + (k0));                      \
    rl1 = *(const uint4*)(Alo + arow + (size_t)64 * K + (k0));     \
    rb0 = *(const uint4*)(Bhi + brow + (k0));                      \
    rbl = *(const uint4*)(Blo + brow + (k0));
#define WRITEL(buf)                                                \
    *(uint4*)&Ash[buf][srow][skc * 8] = ra0;                       \
    *(uint4*)&Ash[buf][srow + 64][skc * 8] = ra1;                  \
    *(uint4*)&Asl[buf][srow][skc * 8] = rl0;                       \
    *(uint4*)&Asl[buf][srow + 64][skc * 8] = rl1;                  \
    *(uint4*)&Bsh[buf][srow][skc * 8] = rb0;                       \
    *(uint4*)&Bsl[buf][srow][skc * 8] = rbl;

    LOADG(0)
    WRITEL(0)
    __syncthreads();

    int cur = 0;
    for (int k0 = 0; k0 < K; k0 += 32) {
        const bool pf = (k0 + 32 < K);
        if (pf) { LOADG(k0 + 32) }
        short8 afh[4], afl[4], bfh[2], bfl[2];
#pragma unroll
        for (int m = 0; m < 4; m++) {
            afh[m] = *(const short8*)&Ash[cur][wr * 64 + m * 16 + l15][lk * 8];
            afl[m] = *(const short8*)&Asl[cur][wr * 64 + m * 16 + l15][lk * 8];
        }
#pragma unroll
        for (int n = 0; n < 2; n++) {
            bfh[n] = *(const short8*)&Bsh[cur][wc * 32 + n * 16 + l15][lk * 8];
            bfl[n] = *(const short8*)&Bsl[cur][wc * 32 + n * 16 + l15][lk * 8];
        }
#pragma unroll
        for (int m = 0; m < 4; m++)
#pragma unroll
            for (int n = 0; n < 2; n++) {
                acc[m][n] = __builtin_amdgcn_mfma_f32_16x16x32_bf16(afh[m], bfh[n], acc[m][n], 0, 0, 0);
                acc[m][n] = __builtin_amdgcn_mfma_f32_16x16x32_bf16(afh[m], bfl[n], acc[m][n], 0, 0, 0);
                acc[m][n] = __builtin_amdgcn_mfma_f32_16x16x32_bf16(afl[m], bfh[n], acc[m][n], 0, 0, 0);
            }
        if (pf) { WRITEL(cur ^ 1) }
        __syncthreads();
        cur ^= 1;
    }
#undef LOADG
#undef WRITEL

#pragma unroll
    for (int m = 0; m < 4; m++) {
#pragma unroll
        for (int n = 0; n < 2; n++) {
            int col = bn + wc * 32 + n * 16 + l15;
#pragma unroll
            for (int r = 0; r < 4; r++) {
                int row = bm + wr * 64 + m * 16 + lk * 4 + r;
                float cval = acc[m][n][r];
                if (OUTM == 0) {
                    out[(size_t)row * Ncol + col] = cval;
                } else {
                    int b = row >> 10, t = row & (Tt - 1);
                    int h = col >> 6, nn2 = col & 63;
                    out[((size_t)(b * Hh + h) * Tt + t) * PACKW + slot * Nn + nn2] = cval;
                }
            }
        }
    }
}

// ===========================================================================
// prep: kk normalize etc
// ===========================================================================
__global__ __launch_bounds__(256) void prep_k(float* __restrict__ pk,
                                              const float* __restrict__ k_k,
                                              const float* __restrict__ k_a)
{
    int inst = blockIdx.x * 4 + (threadIdx.x >> 6);
    int lane = threadIdx.x & 63;
    int b = inst >> 14;
    int rem = inst & 16383;
    int t = rem >> 4;
    int h = rem & 15;
    size_t base = ((size_t)(b * Hh + h) * Tt + t) * PACKW;
    int c = h * 64 + lane;
    float kraw = pk[base + SL_K * 64 + lane];
    float a = pk[base + SL_BV * 64 + lane];
    float kkv = kraw * k_k[c];
    float ss = kkv * kkv;
#pragma unroll
    for (int m = 1; m < 64; m <<= 1) ss += __shfl_xor(ss, m);
    float kkn = kkv / fmaxf(sqrtf(ss), 1e-12f);
    pk[base + SL_NK * 64 + lane] = -kkn;
    pk[base + SL_BV * 64 + lane] = kkn * a;
    pk[base + SL_K * 64 + lane] = kraw * (1.f + (a - 1.f) * k_a[c]);
}

// ===========================================================================
// WKV scan v3: 256 single-wave blocks; 8-deep REGISTER ring (static unroll),
// packed-f32 math, DPP reductions. Compiler manages vmcnt per-use (restrict).
// ===========================================================================
template <int C>
__device__ __forceinline__ float dppmov(float x) {
    return __int_as_float(__builtin_amdgcn_mov_dpp(__float_as_int(x), C, 0xF, 0xF, 1));
}
__device__ __forceinline__ float red8(float v) {
    v += dppmov<0xB1>(v);   // quad_perm xor1
    v += dppmov<0x4E>(v);   // quad_perm xor2
    v += dppmov<0x141>(v);  // row_half_mirror
    return v;
}

__device__ __forceinline__ f32x2 fma2(f32x2 a, f32x2 b, f32x2 c) {
    return __builtin_elementwise_fma(a, b, c);
}

struct Frag {
    f32x2 r[4], w[4], k[4], n[4], b[4];
    float v;
};

__device__ __forceinline__ Frag loadfrag(const float* __restrict__ p, int j0, int i)
{
    Frag f;
    float4 t;
#define LD2(dst, off)                                              \
    t = *(const float4*)(p + (off) + j0);                          \
    dst[0] = (f32x2){t.x, t.y}; dst[1] = (f32x2){t.z, t.w};        \
    t = *(const float4*)(p + (off) + j0 + 4);                      \
    dst[2] = (f32x2){t.x, t.y}; dst[3] = (f32x2){t.z, t.w};
    LD2(f.r, SL_R * 64)
    LD2(f.w, SL_W * 64)
    LD2(f.k, SL_K * 64)
    LD2(f.n, SL_NK * 64)
    LD2(f.b, SL_BV * 64)
#undef LD2
    f.v = p[SL_V * 64 + i];
    return f;
}

__device__ __forceinline__ void stepf(f32x2 S2[4], const Frag& f, int jb, float* optr)
{
    f32x2 d = S2[0] * f.n[0];
    d = fma2(S2[1], f.n[1], d);
    d = fma2(S2[2], f.n[2], d);
    d = fma2(S2[3], f.n[3], d);
    float sa = red8(d.x + d.y);
    f32x2 sa2 = (f32x2){sa, sa};
    f32x2 v2 = (f32x2){f.v, f.v};
#pragma unroll
    for (int e = 0; e < 4; e++)
        S2[e] = fma2(S2[e], f.w[e], fma2(sa2, f.b[e], v2 * f.k[e]));
    f32x2 q = S2[0] * f.r[0];
    q = fma2(S2[1], f.r[1], q);
    q = fma2(S2[2], f.r[2], q);
    q = fma2(S2[3], f.r[3], q);
    float ot = red8(q.x + q.y);
    if (jb == 0) *optr = ot;
}

__global__ __launch_bounds__(64, 1) void wkv_k(const float* __restrict__ pk, float* __restrict__ o)
{
    const int gw = blockIdx.x;              // 0..255
    const int bh = gw >> 3, rg = gw & 7;
    const int lane = threadIdx.x;
    const int ri = lane >> 3, jb = lane & 7, j0 = jb * 8;
    const int i = rg * 8 + ri;
    const int b = bh >> 4, h = bh & 15;
    const float* pb = pk + (size_t)bh * Tt * PACKW;
    float* ob = o + (size_t)b * Tt * Cc + h * 64 + i;

    f32x2 S2[4];
#pragma unroll
    for (int e = 0; e < 4; e++) S2[e] = (f32x2){0.f, 0.f};

    Frag ring[8];
#pragma unroll
    for (int d = 0; d < 8; d++) ring[d] = loadfrag(pb + (size_t)d * PACKW, j0, i);

    for (int t0 = 0; t0 < Tt; t0 += 8) {
#pragma unroll
        for (int u = 0; u < 8; u++) {
            stepf(S2, ring[u], jb, ob + (size_t)(t0 + u) * Cc);
            int tn = t0 + u + 8;
            if (tn > Tt - 1) tn = Tt - 1;
            ring[u] = loadfrag(pb + (size_t)tn * PACKW, j0, i);
        }
    }
}

// ===========================================================================
// post: GroupNorm + rkv + rosa gate + *g -> split bf16 activation
// ===========================================================================
__global__ __launch_bounds__(256) void post_k(
    const float* __restrict__ o, const float* __restrict__ pk, const float* __restrict__ gbuf,
    const float* __restrict__ r_k, const float* __restrict__ ln_w, const float* __restrict__ ln_b,
    const int* __restrict__ ids, const float* __restrict__ emb, const float* __restrict__ rgate,
    unsigned short* __restrict__ outh, unsigned short* __restrict__ outl)
{
    __shared__ float sred[4];
    const int bt = blockIdx.x;
    const int b = bt >> 10, t = bt & 1023;
    const int tid = threadIdx.x;
    const int c0 = tid * 4;
    const int h = tid >> 4;
    const int nn = c0 & 63;

    float4 o4 = *(const float4*)(o + (size_t)bt * Cc + c0);
    float s = o4.x + o4.y + o4.z + o4.w;
    float ss = o4.x * o4.x + o4.y * o4.y + o4.z * o4.z + o4.w * o4.w;
#pragma unroll
    for (int m = 1; m < 16; m <<= 1) { s += __shfl_xor(s, m); ss += __shfl_xor(ss, m); }
    float mu = s * (1.f / 64.f);
    float inv = rsqrtf(ss * (1.f / 64.f) - mu * mu + 0.00064f);

    size_t pbase = ((size_t)(b * Hh + h) * Tt + t) * PACKW;
    float4 r4 = *(const float4*)(pk + pbase + SL_R * 64 + nn);
    float4 k4 = *(const float4*)(pk + pbase + SL_K * 64 + nn);
    float4 v4 = *(const float4*)(pk + pbase + SL_V * 64 + nn);
    float4 q4 = *(const float4*)(r_k + h * 64 + nn);
    float dot = r4.x * k4.x * q4.x + r4.y * k4.y * q4.y + r4.z * k4.z * q4.z + r4.w * k4.w * q4.w;
#pragma unroll
    for (int m = 1; m < 16; m <<= 1) dot += __shfl_xor(dot, m);

    float4 lw = *(const float4*)(ln_w + c0);
    float4 lb = *(const float4*)(ln_b + c0);
    float e0 = (o4.x - mu) * inv * lw.x + lb.x + dot * v4.x;
    float e1 = (o4.y - mu) * inv * lw.y + lb.y + dot * v4.y;
    float e2 = (o4.z - mu) * inv * lw.z + lb.z + dot * v4.z;
    float e3 = (o4.w - mu) * inv * lw.w + lb.w + dot * v4.w;

    float4 rg4 = *(const float4*)(rgate + c0);
    float gp = sigf(e0 * rg4.x) + sigf(e1 * rg4.y) + sigf(e2 * rg4.z) + sigf(e3 * rg4.w);
#pragma unroll
    for (int m = 1; m < 64; m <<= 1) gp += __shfl_xor(gp, m);
    if ((tid & 63) == 0) sred[tid >> 6] = gp;
    __syncthreads();
    float gate = (sred[0] + sred[1] + sred[2] + sred[3]) * (1.f / 1024.f);

    const int id = ids[bt];
    float4 em = *(const float4*)(emb + (size_t)id * Cc + c0);
    float4 g4 = *(const float4*)(gbuf + (size_t)bt * Cc + c0);
    float f0 = (e0 * (1.f - gate) + em.x * gate) * g4.x;
    float f1 = (e1 * (1.f - gate) + em.y * gate) * g4.y;
    float f2 = (e2 * (1.f - gate) + em.z * gate) * g4.z;
    float f3 = (e3 * (1.f - gate) + em.w * gate) * g4.w;
    ushort4 h4, l4;
    h4.x = f2b(f0); l4.x = f2b(f0 - b2f(h4.x));
    h4.y = f2b(f1); l4.y = f2b(f1 - b2f(h4.y));
    h4.z = f2b(f2); l4.z = f2b(f2 - b2f(h4.z));
    h4.w = f2b(f3); l4.w = f2b(f3 - b2f(h4.w));
    *(ushort4*)(outh + (size_t)bt * Cc + c0) = h4;
    *(ushort4*)(outl + (size_t)bt * Cc + c0) = l4;
}

// ===========================================================================
extern "C" void kernel_launch(void* const* d_in, const int* in_sizes, int n_in,
                              void* d_out, int out_size, void* d_ws, size_t ws_size,
                              hipStream_t stream)
{
    (void)in_sizes; (void)n_in; (void)out_size; (void)ws_size;
    const float* x    = (const float*)d_in[0];
    const int*   ids  = (const int*)d_in[1];
    const float* x_r  = (const float*)d_in[2];
    const float* x_w  = (const float*)d_in[3];
    const float* x_k  = (const float*)d_in[4];
    const float* x_v  = (const float*)d_in[5];
    const float* x_a  = (const float*)d_in[6];
    const float* x_g  = (const float*)d_in[7];
    const float* w0   = (const float*)d_in[8];
    const float* a0   = (const float*)d_in[9];
    const float* w1   = (const float*)d_in[11];
    const float* w2   = (const float*)d_in[12];
    const float* a1   = (const float*)d_in[13];
    const float* a2   = (const float*)d_in[14];
    const float* g1   = (const float*)d_in[17];
    const float* g2   = (const float*)d_in[18];
    const float* k_k  = (const float*)d_in[19];
    const float* k_a  = (const float*)d_in[20];
    const float* r_k  = (const float*)d_in[21];
    const float* Wr   = (const float*)d_in[22];
    const float* Wk   = (const float*)d_in[23];
    const float* Wv   = (const float*)d_in[24];
    const float* Wo   = (const float*)d_in[25];
    const float* ln_w = (const float*)d_in[26];
    const float* ln_b = (const float*)d_in[27];
    const float* emb  = (const float*)d_in[28];
    const float* rg   = (const float*)d_in[29];

    float* ws = (float*)d_ws;
    float* pack = ws;                                          // 12,582,912 f
    float* obuf = pack + (size_t)12582912;                     // 2,097,152 f
    float* gbuf = obuf + (size_t)2097152;                      // 2,097,152 f
    float* hw   = gbuf + (size_t)2097152;                      // 131072
    float* ha   = hw + (size_t)131072;                         // 131072
    float* hg   = ha + (size_t)131072;                         // 262144
    unsigned short* u = (unsigned short*)(hg + (size_t)262144);
    unsigned short* xrh = u;                    // each 2,097,152 ushorts
    unsigned short* xrl = xrh + (size_t)2097152;
    unsigned short* xkh = xrl + (size_t)2097152;
    unsigned short* xkl = xkh + (size_t)2097152;
    unsigned short* xvh = xkl + (size_t)2097152;
    unsigned short* xvl = xvh + (size_t)2097152;
    unsigned short* wth = xvl + (size_t)2097152;   // 4 x 1,048,576
    unsigned short* wtl = wth + (size_t)4194304;   // 4 x 1,048,576
    // obufb hi/lo alias xr (dead after the R projection)
    unsigned short* obh = xrh;
    unsigned short* obl = xrl;

    dim3 blk(256);

    wtrans_k<<<dim3(16, 16, 4), blk, 0, stream>>>(Wr, Wk, Wv, Wo, wth, wtl);
    mixcast_k<<<dim3(2048), blk, 0, stream>>>(x, x_r, x_k, x_v, xrh, xrl, xkh, xkl, xvh, xvl);

    // r, k, v projections via split bf16 MFMA -> pack slots (f32 quality)
    dim3 gmm(Cc / 64, Mtot / 128);   // (16,16) = 256 blocks
    mgemm3_k<1><<<gmm, blk, 0, stream>>>(xrh, xrl, wth + (size_t)0 * 1048576, wtl + (size_t)0 * 1048576, pack, Mtot, Cc, Cc, SL_R);
    mgemm3_k<1><<<gmm, blk, 0, stream>>>(xkh, xkl, wth + (size_t)1 * 1048576, wtl + (size_t)1 * 1048576, pack, Mtot, Cc, Cc, SL_K);
    mgemm3_k<1><<<gmm, blk, 0, stream>>>(xvh, xvl, wth + (size_t)2 * 1048576, wtl + (size_t)2 * 1048576, pack, Mtot, Cc, Cc, SL_V);

    // w = exp(-exp(w0 + tanh(xw@w1)@w2)) -> SL_W
    gemm_k<64, 64, 16, 4, 4, 1, 0, 1, 0><<<dim3(1, 32), blk, 0, stream>>>(x, w1, x_w, nullptr, hw, Mtot, 64, Cc, 0);
    gemm_k<64, 64, 16, 4, 4, 0, 1, 3, 1><<<dim3(16, 32), blk, 0, stream>>>(hw, w2, nullptr, w0, pack, Mtot, Cc, 64, SL_W);
    // a = sigmoid(a0 + (xa@a1)@a2) -> SL_BV (temp)
    gemm_k<64, 64, 16, 4, 4, 1, 0, 0, 0><<<dim3(1, 32), blk, 0, stream>>>(x, a1, x_a, nullptr, ha, Mtot, 64, Cc, 0);
    gemm_k<64, 64, 16, 4, 4, 0, 1, 2, 1><<<dim3(16, 32), blk, 0, stream>>>(ha, a2, nullptr, a0, pack, Mtot, Cc, 64, SL_BV);
    // g = sigmoid(xg@g1)@g2 -> gbuf
    gemm_k<64, 64, 16, 4, 4, 1, 0, 2, 0><<<dim3(2, 32), blk, 0, stream>>>(x, g1, x_g, nullptr, hg, Mtot, 128, Cc, 0);
    gemm_k<64, 64, 16, 4, 4, 0, 0, 0, 0><<<dim3(16, 32), blk, 0, stream>>>(hg, g2, nullptr, nullptr, gbuf, Mtot, Cc, 128, 0);

    prep_k<<<dim3(Bb * Tt * Hh / 4), blk, 0, stream>>>(pack, k_k, k_a);
    wkv_k<<<dim3(256), dim3(64), 0, stream>>>(pack, obuf);
    post_k<<<dim3(Mtot), blk, 0, stream>>>(obuf, pack, gbuf, r_k, ln_w, ln_b, ids, emb, rg, obh, obl);
    mgemm3_k<0><<<gmm, blk, 0, stream>>>(obh, obl, wth + (size_t)3 * 1048576, wtl + (size_t)3 * 1048576, (float*)d_out, Mtot, Cc, Cc, 0);
}

// Round 5
// 436.823 us; speedup vs baseline: 3.0258x; 1.2451x over previous
//
#include <hip/hip_runtime.h>
#include <hip/hip_bf16.h>
#include <hip/hip_fp16.h>
#include <math.h>

// RWKV-7 Tmix: B=2, T=1024, C=1024, H=16, N=64
constexpr int Bb = 2, Tt = 1024, Cc = 1024, Hh = 16, Nn = 64;
constexpr int Mtot = Bb * Tt;          // 2048 rows
constexpr int PACKW = 6 * Nn;          // 384 floats per (b,h,t)
constexpr int SL_R = 0, SL_W = 1, SL_K = 2, SL_V = 3, SL_NK = 4, SL_BV = 5;

__device__ __forceinline__ float sigf(float x) { return 1.f / (1.f + expf(-x)); }

__device__ __forceinline__ unsigned short f2h(float f) {
    _Float16 h = (_Float16)f;
    return __builtin_bit_cast(unsigned short, h);
}

// ===========================================================================
// f32 tiled GEMM (low-rank chains only). TM may be 1 (generic frag loader).
// ===========================================================================
template <int BM, int BN, int BK, int TM, int TN, int MIX, int BIAS, int EPI, int OUTM>
__global__ __launch_bounds__((BM / TM) * (BN / TN)) void gemm_k(
    const float* __restrict__ A, const float* __restrict__ W,
    const float* __restrict__ mixv, const float* __restrict__ bias,
    float* __restrict__ out, int M, int Ncol, int K, int slot)
{
    constexpr int NT = (BM / TM) * (BN / TN);
    constexpr int A4 = BM * BK / 4;
    constexpr int B4 = BK * BN / 4;
    __shared__ float As[BK][BM + 4];
    __shared__ float Bs[BK][BN];
    const int tid = threadIdx.x;
    const int bm = blockIdx.y * BM;
    const int bn = blockIdx.x * BN;
    const int tx = tid % (BN / TN);
    const int ty = tid / (BN / TN);

    float acc[TM][TN];
#pragma unroll
    for (int i = 0; i < TM; i++)
#pragma unroll
        for (int j = 0; j < TN; j++) acc[i][j] = 0.f;

    for (int k0 = 0; k0 < K; k0 += BK) {
        for (int i = tid; i < A4; i += NT) {
            int row = i / (BK / 4), kq = i % (BK / 4);
            int m = bm + row, kb = k0 + kq * 4;
            float4 xv = *(const float4*)(A + (size_t)m * K + kb);
            if (MIX) {
                int t = m & (Tt - 1);
                float4 xp = make_float4(0.f, 0.f, 0.f, 0.f);
                if (t) xp = *(const float4*)(A + (size_t)(m - 1) * K + kb);
                float4 mv = *(const float4*)(mixv + kb);
                xv.x += (xp.x - xv.x) * mv.x;
                xv.y += (xp.y - xv.y) * mv.y;
                xv.z += (xp.z - xv.z) * mv.z;
                xv.w += (xp.w - xv.w) * mv.w;
            }
            As[kq * 4 + 0][row] = xv.x;
            As[kq * 4 + 1][row] = xv.y;
            As[kq * 4 + 2][row] = xv.z;
            As[kq * 4 + 3][row] = xv.w;
        }
        for (int i = tid; i < B4; i += NT) {
            int kr = i / (BN / 4), nq = i % (BN / 4);
            float4 wv = *(const float4*)(W + (size_t)(k0 + kr) * Ncol + bn + nq * 4);
            *(float4*)&Bs[kr][nq * 4] = wv;
        }
        __syncthreads();
#pragma unroll
        for (int kk = 0; kk < BK; kk++) {
            float av[TM], bv[TN];
            if constexpr (TM % 4 == 0) {
#pragma unroll
                for (int i = 0; i < TM; i += 4) {
                    float4 t4 = *(const float4*)&As[kk][ty * TM + i];
                    av[i] = t4.x; av[i + 1] = t4.y; av[i + 2] = t4.z; av[i + 3] = t4.w;
                }
            } else {
#pragma unroll
                for (int i = 0; i < TM; i++) av[i] = As[kk][ty * TM + i];
            }
#pragma unroll
            for (int j = 0; j < TN; j += 4) {
                float4 t4 = *(const float4*)&Bs[kk][tx * TN + j];
                bv[j] = t4.x; bv[j + 1] = t4.y; bv[j + 2] = t4.z; bv[j + 3] = t4.w;
            }
#pragma unroll
            for (int i = 0; i < TM; i++)
#pragma unroll
                for (int j = 0; j < TN; j++) acc[i][j] += av[i] * bv[j];
        }
        __syncthreads();
    }

#pragma unroll
    for (int i = 0; i < TM; i++) {
        int m = bm + ty * TM + i;
#pragma unroll
        for (int j = 0; j < TN; j++) {
            int n = bn + tx * TN + j;
            float c = acc[i][j];
            if (BIAS) c += bias[n];
            if (EPI == 1) c = tanhf(c);
            else if (EPI == 2) c = sigf(c);
            else if (EPI == 3) c = expf(-expf(c));
            if (OUTM == 0) {
                out[(size_t)m * Ncol + n] = c;
            } else {
                int b = m >> 10, t = m & (Tt - 1);
                int h = n >> 6, nn2 = n & 63;
                out[((size_t)(b * Hh + h) * Tt + t) * PACKW + slot * Nn + nn2] = c;
            }
        }
    }
}

// ===========================================================================
// mix + cast to f16: xr, xk, xv  [2048][1024] (contiguous: xf + z*2M)
// ===========================================================================
__global__ __launch_bounds__(256) void mixcast_k(
    const float* __restrict__ x, const float* __restrict__ mr,
    const float* __restrict__ mk, const float* __restrict__ mv,
    unsigned short* __restrict__ xf)
{
    int idx = (blockIdx.x * 256 + threadIdx.x) * 4;
    int m = idx >> 10, c = idx & 1023;
    int t = m & (Tt - 1);
    float4 xc = *(const float4*)(x + idx);
    float4 xp = make_float4(0.f, 0.f, 0.f, 0.f);
    if (t) xp = *(const float4*)(x + idx - Cc);
    float4 d = make_float4(xp.x - xc.x, xp.y - xc.y, xp.z - xc.z, xp.w - xc.w);
    float4 m4;
    ushort4 o4;
#define EMIT(mixp, zoff)                                               \
    m4 = *(const float4*)(mixp + c);                                   \
    o4.x = f2h(xc.x + d.x * m4.x); o4.y = f2h(xc.y + d.y * m4.y);      \
    o4.z = f2h(xc.z + d.z * m4.z); o4.w = f2h(xc.w + d.w * m4.w);      \
    *(ushort4*)(xf + (size_t)(zoff)*2097152 + idx) = o4;
    EMIT(mr, 0)
    EMIT(mk, 1)
    EMIT(mv, 2)
#undef EMIT
}

// ===========================================================================
// weight transpose + cast to f16: WT[n][k] from W[k][n] f32. 64x64 tiles.
// ===========================================================================
__global__ __launch_bounds__(256) void wtrans_k(
    const float* __restrict__ W0, const float* __restrict__ W1,
    const float* __restrict__ W2, const float* __restrict__ W3,
    unsigned short* __restrict__ WT)
{
    __shared__ float ls[64][65];
    const int z = blockIdx.z;
    const float* W = (z == 0) ? W0 : (z == 1) ? W1 : (z == 2) ? W2 : W3;
    unsigned short* dst = WT + (size_t)z * Cc * Cc;
    const int k0 = blockIdx.x * 64, n0 = blockIdx.y * 64;
    const int tid = threadIdx.x;
    const int rr = tid >> 4, c4 = tid & 15;
#pragma unroll
    for (int q = 0; q < 4; q++) {
        int kr = rr + q * 16;
        float4 v = *(const float4*)(W + (size_t)(k0 + kr) * Cc + n0 + c4 * 4);
        ls[kr][c4 * 4 + 0] = v.x; ls[kr][c4 * 4 + 1] = v.y;
        ls[kr][c4 * 4 + 2] = v.z; ls[kr][c4 * 4 + 3] = v.w;
    }
    __syncthreads();
#pragma unroll
    for (int q = 0; q < 4; q++) {
        int nr = rr + q * 16;
        ushort4 o;
        o.x = f2h(ls[c4 * 4 + 0][nr]);
        o.y = f2h(ls[c4 * 4 + 1][nr]);
        o.z = f2h(ls[c4 * 4 + 2][nr]);
        o.w = f2h(ls[c4 * 4 + 3][nr]);
        *(ushort4*)(dst + (size_t)(n0 + nr) * Cc + k0 + c4 * 4) = o;
    }
}

// ===========================================================================
// f16 MFMA GEMM: out = A[M,K] @ WT[N,K]^T. 128x64 tile, 4 waves, dbuf LDS.
// RKV==1: blockIdx.z in {0,1,2} picks (xr,xk,xv) and pack slot (scatter out).
// RKV==0: plain row-major f32 out.
// ===========================================================================
typedef _Float16 half8 __attribute__((ext_vector_type(8)));
typedef float f32x4 __attribute__((ext_vector_type(4)));

template <int RKV>
__global__ __launch_bounds__(256) void mgemm_k(
    const unsigned short* __restrict__ Abase, const unsigned short* __restrict__ WT,
    float* __restrict__ out, int M, int Ncol, int K)
{
    __shared__ unsigned short Ash[2][128][40];
    __shared__ unsigned short Bsh[2][64][40];
    const int z = RKV ? blockIdx.z : 0;
    const unsigned short* A = Abase + (size_t)z * 2097152;
    const unsigned short* BT = WT + (size_t)z * 1048576;
    const int tid = threadIdx.x;
    const int lane = tid & 63, wid = tid >> 6;
    const int wr = wid >> 1, wc = wid & 1;
    const int bm = blockIdx.y * 128, bn = blockIdx.x * 64;
    const int l15 = lane & 15, lk = lane >> 4;
    const int srow = tid >> 2, skc = tid & 3;

    f32x4 acc[4][2];
#pragma unroll
    for (int i = 0; i < 4; i++)
#pragma unroll
        for (int j = 0; j < 2; j++) acc[i][j] = (f32x4){0.f, 0.f, 0.f, 0.f};

    uint4 ra0, ra1, rb0;
    const size_t arow = (size_t)(bm + srow) * K + skc * 8;
    const size_t brow = (size_t)(bn + srow) * K + skc * 8;

#define LOADG(k0)                                                  \
    ra0 = *(const uint4*)(A + arow + (k0));                        \
    ra1 = *(const uint4*)(A + arow + (size_t)64 * K + (k0));       \
    rb0 = *(const uint4*)(BT + brow + (k0));
#define WRITEL(buf)                                                \
    *(uint4*)&Ash[buf][srow][skc * 8] = ra0;                       \
    *(uint4*)&Ash[buf][srow + 64][skc * 8] = ra1;                  \
    *(uint4*)&Bsh[buf][srow][skc * 8] = rb0;

    LOADG(0)
    WRITEL(0)
    __syncthreads();

    int cur = 0;
    for (int k0 = 0; k0 < K; k0 += 32) {
        const bool pf = (k0 + 32 < K);
        if (pf) { LOADG(k0 + 32) }
        half8 af[4], bf[2];
#pragma unroll
        for (int m = 0; m < 4; m++)
            af[m] = *(const half8*)&Ash[cur][wr * 64 + m * 16 + l15][lk * 8];
#pragma unroll
        for (int n = 0; n < 2; n++)
            bf[n] = *(const half8*)&Bsh[cur][wc * 32 + n * 16 + l15][lk * 8];
#pragma unroll
        for (int m = 0; m < 4; m++)
#pragma unroll
            for (int n = 0; n < 2; n++)
                acc[m][n] = __builtin_amdgcn_mfma_f32_16x16x32_f16(af[m], bf[n], acc[m][n], 0, 0, 0);
        if (pf) { WRITEL(cur ^ 1) }
        __syncthreads();
        cur ^= 1;
    }
#undef LOADG
#undef WRITEL

    const int slots[3] = {SL_R, SL_K, SL_V};
    const int slot = slots[z];
#pragma unroll
    for (int m = 0; m < 4; m++) {
#pragma unroll
        for (int n = 0; n < 2; n++) {
            int col = bn + wc * 32 + n * 16 + l15;
#pragma unroll
            for (int r = 0; r < 4; r++) {
                int row = bm + wr * 64 + m * 16 + lk * 4 + r;
                float cval = acc[m][n][r];
                if (RKV == 0) {
                    out[(size_t)row * Ncol + col] = cval;
                } else {
                    int b = row >> 10, t = row & (Tt - 1);
                    int h = col >> 6, nn2 = col & 63;
                    out[((size_t)(b * Hh + h) * Tt + t) * PACKW + slot * Nn + nn2] = cval;
                }
            }
        }
    }
}

// ===========================================================================
// prep: kk normalize etc
// ===========================================================================
__global__ __launch_bounds__(256) void prep_k(float* __restrict__ pk,
                                              const float* __restrict__ k_k,
                                              const float* __restrict__ k_a)
{
    int inst = blockIdx.x * 4 + (threadIdx.x >> 6);
    int lane = threadIdx.x & 63;
    int b = inst >> 14;
    int rem = inst & 16383;
    int t = rem >> 4;
    int h = rem & 15;
    size_t base = ((size_t)(b * Hh + h) * Tt + t) * PACKW;
    int c = h * 64 + lane;
    float kraw = pk[base + SL_K * 64 + lane];
    float a = pk[base + SL_BV * 64 + lane];
    float kkv = kraw * k_k[c];
    float ss = kkv * kkv;
#pragma unroll
    for (int m = 1; m < 64; m <<= 1) ss += __shfl_xor(ss, m);
    float kkn = kkv / fmaxf(sqrtf(ss), 1e-12f);
    pk[base + SL_NK * 64 + lane] = -kkn;
    pk[base + SL_BV * 64 + lane] = kkn * a;
    pk[base + SL_K * 64 + lane] = kraw * (1.f + (a - 1.f) * k_a[c]);
}

// ===========================================================================
// WKV scan v5: 512 one-wave blocks (2/CU), 4 rows/wave (16 lanes/row, 4 cols/
// lane), 8-deep register ring (frag=21 regs -> fits), XCD-aware block remap,
// 4-stage pure-DPP reduction.
// ===========================================================================
template <int C>
__device__ __forceinline__ float dppmov(float x) {
    return __int_as_float(__builtin_amdgcn_mov_dpp(__float_as_int(x), C, 0xF, 0xF, 1));
}
__device__ __forceinline__ float red16(float v) {
    v += dppmov<0xB1>(v);   // quad_perm xor1
    v += dppmov<0x4E>(v);   // quad_perm xor2
    v += dppmov<0x141>(v);  // row_half_mirror: pairs of quads
    v += dppmov<0x140>(v);  // row_mirror: pairs of 8-groups
    return v;
}

struct Frag4 {
    float4 r, w, k, n, b;
    float v;
};

__device__ __forceinline__ Frag4 loadfrag4(const float* __restrict__ p, int j0, int i)
{
    Frag4 f;
    f.r = *(const float4*)(p + SL_R * 64 + j0);
    f.w = *(const float4*)(p + SL_W * 64 + j0);
    f.k = *(const float4*)(p + SL_K * 64 + j0);
    f.n = *(const float4*)(p + SL_NK * 64 + j0);
    f.b = *(const float4*)(p + SL_BV * 64 + j0);
    f.v = p[SL_V * 64 + i];
    return f;
}

__device__ __forceinline__ void stepf(float4& S, const Frag4& f, int jb, float* optr)
{
    float sa = fmaf(S.w, f.n.w, fmaf(S.z, f.n.z, fmaf(S.y, f.n.y, S.x * f.n.x)));
    sa = red16(sa);
    S.x = fmaf(S.x, f.w.x, fmaf(sa, f.b.x, f.v * f.k.x));
    S.y = fmaf(S.y, f.w.y, fmaf(sa, f.b.y, f.v * f.k.y));
    S.z = fmaf(S.z, f.w.z, fmaf(sa, f.b.z, f.v * f.k.z));
    S.w = fmaf(S.w, f.w.w, fmaf(sa, f.b.w, f.v * f.k.w));
    float ot = fmaf(S.w, f.r.w, fmaf(S.z, f.r.z, fmaf(S.y, f.r.y, S.x * f.r.x)));
    ot = red16(ot);
    if (jb == 0) *optr = ot;
}

__global__ __launch_bounds__(64, 1) void wkv_k(const float* __restrict__ pk, float* __restrict__ o)
{
    // XCD-aware remap: all 16 row-group waves of one bh land on one XCD.
    const int bx = blockIdx.x;          // 0..511
    const int xcd = bx & 7;
    const int ix = bx >> 3;             // 0..63
    const int bh = ((ix >> 4) << 3) | xcd;
    const int rg = ix & 15;
    const int lane = threadIdx.x;
    const int ri = lane >> 4, jb = lane & 15, j0 = jb * 4;
    const int i = rg * 4 + ri;
    const int b = bh >> 4, h = bh & 15;
    const float* pb = pk + (size_t)bh * Tt * PACKW;
    float* ob = o + (size_t)b * Tt * Cc + h * 64 + i;

    float4 S = make_float4(0.f, 0.f, 0.f, 0.f);

    Frag4 ring[8];
#pragma unroll
    for (int d = 0; d < 8; d++) ring[d] = loadfrag4(pb + (size_t)d * PACKW, j0, i);

    for (int t0 = 0; t0 < Tt; t0 += 8) {
#pragma unroll
        for (int u = 0; u < 8; u++) {
            stepf(S, ring[u], jb, ob + (size_t)(t0 + u) * Cc);
            int tn = t0 + u + 8;
            if (tn > Tt - 1) tn = Tt - 1;
            ring[u] = loadfrag4(pb + (size_t)tn * PACKW, j0, i);
        }
    }
}

// ===========================================================================
// post: GroupNorm + rkv + rosa gate + *g -> f16 activation
// ===========================================================================
__global__ __launch_bounds__(256) void post_k(
    const float* __restrict__ o, const float* __restrict__ pk, const float* __restrict__ gbuf,
    const float* __restrict__ r_k, const float* __restrict__ ln_w, const float* __restrict__ ln_b,
    const int* __restrict__ ids, const float* __restrict__ emb, const float* __restrict__ rgate,
    unsigned short* __restrict__ outh)
{
    __shared__ float sred[4];
    const int bt = blockIdx.x;
    const int b = bt >> 10, t = bt & 1023;
    const int tid = threadIdx.x;
    const int c0 = tid * 4;
    const int h = tid >> 4;
    const int nn = c0 & 63;

    float4 o4 = *(const float4*)(o + (size_t)bt * Cc + c0);
    float s = o4.x + o4.y + o4.z + o4.w;
    float ss = o4.x * o4.x + o4.y * o4.y + o4.z * o4.z + o4.w * o4.w;
#pragma unroll
    for (int m = 1; m < 16; m <<= 1) { s += __shfl_xor(s, m); ss += __shfl_xor(ss, m); }
    float mu = s * (1.f / 64.f);
    float inv = rsqrtf(ss * (1.f / 64.f) - mu * mu + 0.00064f);

    size_t pbase = ((size_t)(b * Hh + h) * Tt + t) * PACKW;
    float4 r4 = *(const float4*)(pk + pbase + SL_R * 64 + nn);
    float4 k4 = *(const float4*)(pk + pbase + SL_K * 64 + nn);
    float4 v4 = *(const float4*)(pk + pbase + SL_V * 64 + nn);
    float4 q4 = *(const float4*)(r_k + h * 64 + nn);
    float dot = r4.x * k4.x * q4.x + r4.y * k4.y * q4.y + r4.z * k4.z * q4.z + r4.w * k4.w * q4.w;
#pragma unroll
    for (int m = 1; m < 16; m <<= 1) dot += __shfl_xor(dot, m);

    float4 lw = *(const float4*)(ln_w + c0);
    float4 lb = *(const float4*)(ln_b + c0);
    float e0 = (o4.x - mu) * inv * lw.x + lb.x + dot * v4.x;
    float e1 = (o4.y - mu) * inv * lw.y + lb.y + dot * v4.y;
    float e2 = (o4.z - mu) * inv * lw.z + lb.z + dot * v4.z;
    float e3 = (o4.w - mu) * inv * lw.w + lb.w + dot * v4.w;

    float4 rg4 = *(const float4*)(rgate + c0);
    float gp = sigf(e0 * rg4.x) + sigf(e1 * rg4.y) + sigf(e2 * rg4.z) + sigf(e3 * rg4.w);
#pragma unroll
    for (int m = 1; m < 64; m <<= 1) gp += __shfl_xor(gp, m);
    if ((tid & 63) == 0) sred[tid >> 6] = gp;
    __syncthreads();
    float gate = (sred[0] + sred[1] + sred[2] + sred[3]) * (1.f / 1024.f);

    const int id = ids[bt];
    float4 em = *(const float4*)(emb + (size_t)id * Cc + c0);
    float4 g4 = *(const float4*)(gbuf + (size_t)bt * Cc + c0);
    ushort4 h4;
    h4.x = f2h((e0 * (1.f - gate) + em.x * gate) * g4.x);
    h4.y = f2h((e1 * (1.f - gate) + em.y * gate) * g4.y);
    h4.z = f2h((e2 * (1.f - gate) + em.z * gate) * g4.z);
    h4.w = f2h((e3 * (1.f - gate) + em.w * gate) * g4.w);
    *(ushort4*)(outh + (size_t)bt * Cc + c0) = h4;
}

// ===========================================================================
extern "C" void kernel_launch(void* const* d_in, const int* in_sizes, int n_in,
                              void* d_out, int out_size, void* d_ws, size_t ws_size,
                              hipStream_t stream)
{
    (void)in_sizes; (void)n_in; (void)out_size; (void)ws_size;
    const float* x    = (const float*)d_in[0];
    const int*   ids  = (const int*)d_in[1];
    const float* x_r  = (const float*)d_in[2];
    const float* x_w  = (const float*)d_in[3];
    const float* x_k  = (const float*)d_in[4];
    const float* x_v  = (const float*)d_in[5];
    const float* x_a  = (const float*)d_in[6];
    const float* x_g  = (const float*)d_in[7];
    const float* w0   = (const float*)d_in[8];
    const float* a0   = (const float*)d_in[9];
    const float* w1   = (const float*)d_in[11];
    const float* w2   = (const float*)d_in[12];
    const float* a1   = (const float*)d_in[13];
    const float* a2   = (const float*)d_in[14];
    const float* g1   = (const float*)d_in[17];
    const float* g2   = (const float*)d_in[18];
    const float* k_k  = (const float*)d_in[19];
    const float* k_a  = (const float*)d_in[20];
    const float* r_k  = (const float*)d_in[21];
    const float* Wr   = (const float*)d_in[22];
    const float* Wk   = (const float*)d_in[23];
    const float* Wv   = (const float*)d_in[24];
    const float* Wo   = (const float*)d_in[25];
    const float* ln_w = (const float*)d_in[26];
    const float* ln_b = (const float*)d_in[27];
    const float* emb  = (const float*)d_in[28];
    const float* rg   = (const float*)d_in[29];

    float* ws = (float*)d_ws;
    float* pack = ws;                                          // 12,582,912 f
    float* obuf = pack + (size_t)12582912;                     // 2,097,152 f
    float* gbuf = obuf + (size_t)2097152;                      // 2,097,152 f
    float* hw   = gbuf + (size_t)2097152;                      // 131072
    float* ha   = hw + (size_t)131072;                         // 131072
    float* hg   = ha + (size_t)131072;                         // 262144
    unsigned short* xf = (unsigned short*)(hg + (size_t)262144);  // 3 x 2,097,152 (xr,xk,xv)
    unsigned short* wt = xf + (size_t)3 * 2097152;                // 4 x 1,048,576 (Wr,Wk,Wv,Wo ^T)
    unsigned short* obh = xf;   // final activation aliases xr (dead after R proj)

    dim3 blk(256);

    wtrans_k<<<dim3(16, 16, 4), blk, 0, stream>>>(Wr, Wk, Wv, Wo, wt);
    mixcast_k<<<dim3(2048), blk, 0, stream>>>(x, x_r, x_k, x_v, xf);

    // r, k, v projections: one merged f16-MFMA launch (z in {0,1,2})
    mgemm_k<1><<<dim3(Cc / 64, Mtot / 128, 3), blk, 0, stream>>>(xf, wt, pack, Mtot, Cc, Cc);

    // w = exp(-exp(w0 + tanh(xw@w1)@w2)) -> SL_W
    gemm_k<16, 64, 16, 1, 4, 1, 0, 1, 0><<<dim3(1, 128), blk, 0, stream>>>(x, w1, x_w, nullptr, hw, Mtot, 64, Cc, 0);
    gemm_k<64, 64, 16, 4, 4, 0, 1, 3, 1><<<dim3(16, 32), blk, 0, stream>>>(hw, w2, nullptr, w0, pack, Mtot, Cc, 64, SL_W);
    // a = sigmoid(a0 + (xa@a1)@a2) -> SL_BV (temp)
    gemm_k<16, 64, 16, 1, 4, 1, 0, 0, 0><<<dim3(1, 128), blk, 0, stream>>>(x, a1, x_a, nullptr, ha, Mtot, 64, Cc, 0);
    gemm_k<64, 64, 16, 4, 4, 0, 1, 2, 1><<<dim3(16, 32), blk, 0, stream>>>(ha, a2, nullptr, a0, pack, Mtot, Cc, 64, SL_BV);
    // g = sigmoid(xg@g1)@g2 -> gbuf
    gemm_k<16, 64, 16, 1, 4, 1, 0, 2, 0><<<dim3(2, 128), blk, 0, stream>>>(x, g1, x_g, nullptr, hg, Mtot, 128, Cc, 0);
    gemm_k<64, 64, 16, 4, 4, 0, 0, 0, 0><<<dim3(16, 32), blk, 0, stream>>>(hg, g2, nullptr, nullptr, gbuf, Mtot, Cc, 128, 0);

    prep_k<<<dim3(Bb * Tt * Hh / 4), blk, 0, stream>>>(pack, k_k, k_a);
    wkv_k<<<dim3(512), dim3(64), 0, stream>>>(pack, obuf);
    post_k<<<dim3(Mtot), blk, 0, stream>>>(obuf, pack, gbuf, r_k, ln_w, ln_b, ids, emb, rg, obh);
    mgemm_k<0><<<dim3(Cc / 64, Mtot / 128, 1), blk, 0, stream>>>(obh, wt + (size_t)3 * 1048576, (float*)d_out, Mtot, Cc, Cc);
}

// Round 6
// 233.438 us; speedup vs baseline: 5.6620x; 1.8713x over previous
//
#include <hip/hip_runtime.h>
#include <hip/hip_bf16.h>
#include <hip/hip_fp16.h>
#include <math.h>

// RWKV-7 Tmix: B=2, T=1024, C=1024, H=16, N=64
constexpr int Bb = 2, Tt = 1024, Cc = 1024, Hh = 16, Nn = 64;
constexpr int Mtot = Bb * Tt;          // 2048 rows
constexpr int PACKW = 6 * Nn;          // 384 floats per (b,h,t)
constexpr int SL_R = 0, SL_W = 1, SL_K = 2, SL_V = 3, SL_NK = 4, SL_BV = 5;

typedef _Float16 half8 __attribute__((ext_vector_type(8)));
typedef float f32x4 __attribute__((ext_vector_type(4)));

__device__ __forceinline__ float sigf(float x) { return 1.f / (1.f + expf(-x)); }

__device__ __forceinline__ unsigned short f2h(float f) {
    _Float16 h = (_Float16)f;
    return __builtin_bit_cast(unsigned short, h);
}

// ===========================================================================
// mix + cast to f16: xr,xk,xv,xw,xa,xg  (xf + z*2M), z = 0..5
// ===========================================================================
__global__ __launch_bounds__(256) void mixcast_k(
    const float* __restrict__ x, const float* __restrict__ mr,
    const float* __restrict__ mk, const float* __restrict__ mv,
    const float* __restrict__ mw, const float* __restrict__ ma,
    const float* __restrict__ mg, unsigned short* __restrict__ xf)
{
    int idx = (blockIdx.x * 256 + threadIdx.x) * 4;
    int m = idx >> 10, c = idx & 1023;
    int t = m & (Tt - 1);
    float4 xc = *(const float4*)(x + idx);
    float4 xp = make_float4(0.f, 0.f, 0.f, 0.f);
    if (t) xp = *(const float4*)(x + idx - Cc);
    float4 d = make_float4(xp.x - xc.x, xp.y - xc.y, xp.z - xc.z, xp.w - xc.w);
    float4 m4;
    ushort4 o4;
#define EMIT(mixp, zoff)                                               \
    m4 = *(const float4*)(mixp + c);                                   \
    o4.x = f2h(xc.x + d.x * m4.x); o4.y = f2h(xc.y + d.y * m4.y);      \
    o4.z = f2h(xc.z + d.z * m4.z); o4.w = f2h(xc.w + d.w * m4.w);      \
    *(ushort4*)(xf + (size_t)(zoff)*2097152 + idx) = o4;
    EMIT(mr, 0)
    EMIT(mk, 1)
    EMIT(mv, 2)
    EMIT(mw, 3)
    EMIT(ma, 4)
    EMIT(mg, 5)
#undef EMIT
}

// ===========================================================================
// big weight transpose + cast f16: WT[n][k] from W[k][n]. 64x64 tiles, z=0..3
// ===========================================================================
__global__ __launch_bounds__(256) void wtrans_k(
    const float* __restrict__ W0, const float* __restrict__ W1,
    const float* __restrict__ W2, const float* __restrict__ W3,
    unsigned short* __restrict__ WT)
{
    __shared__ float ls[64][65];
    const int z = blockIdx.z;
    const float* W = (z == 0) ? W0 : (z == 1) ? W1 : (z == 2) ? W2 : W3;
    unsigned short* dst = WT + (size_t)z * Cc * Cc;
    const int k0 = blockIdx.x * 64, n0 = blockIdx.y * 64;
    const int tid = threadIdx.x;
    const int rr = tid >> 4, c4 = tid & 15;
#pragma unroll
    for (int q = 0; q < 4; q++) {
        int kr = rr + q * 16;
        float4 v = *(const float4*)(W + (size_t)(k0 + kr) * Cc + n0 + c4 * 4);
        ls[kr][c4 * 4 + 0] = v.x; ls[kr][c4 * 4 + 1] = v.y;
        ls[kr][c4 * 4 + 2] = v.z; ls[kr][c4 * 4 + 3] = v.w;
    }
    __syncthreads();
#pragma unroll
    for (int q = 0; q < 4; q++) {
        int nr = rr + q * 16;
        ushort4 o;
        o.x = f2h(ls[c4 * 4 + 0][nr]);
        o.y = f2h(ls[c4 * 4 + 1][nr]);
        o.z = f2h(ls[c4 * 4 + 2][nr]);
        o.w = f2h(ls[c4 * 4 + 3][nr]);
        *(ushort4*)(dst + (size_t)(n0 + nr) * Cc + k0 + c4 * 4) = o;
    }
}

// ===========================================================================
// 6 small low-rank weight transposes -> f16, one launch (128 tile-blocks).
// wts layout (ushort elems): w1T@0 [64][1024], a1T@65536, g1T@131072 [128][1024],
//                            w2T@262144 [1024][64], a2T@327680, g2T@393216 [1024][128]
// ===========================================================================
__global__ __launch_bounds__(256) void tr6_k(
    const float* __restrict__ w1, const float* __restrict__ a1, const float* __restrict__ g1,
    const float* __restrict__ w2, const float* __restrict__ a2, const float* __restrict__ g2,
    unsigned short* __restrict__ wts)
{
    int t = blockIdx.x;
    const float* src; unsigned short* dst; int R, C, tr, tc;
    if (t < 16)      { src = w1; dst = wts + 0;      R = 1024; C = 64;   tr = t;            tc = 0; }
    else if (t < 32) { src = a1; dst = wts + 65536;  R = 1024; C = 64;   tr = t - 16;       tc = 0; }
    else if (t < 64) { src = g1; dst = wts + 131072; R = 1024; C = 128;  tr = (t - 32) >> 1; tc = (t - 32) & 1; }
    else if (t < 80) { src = w2; dst = wts + 262144; R = 64;   C = 1024; tr = 0;            tc = t - 64; }
    else if (t < 96) { src = a2; dst = wts + 327680; R = 64;   C = 1024; tr = 0;            tc = t - 80; }
    else             { src = g2; dst = wts + 393216; R = 128;  C = 1024; tr = (t - 96) & 1; tc = (t - 96) >> 1; }
    __shared__ float ls[64][65];
    const int tid = threadIdx.x, rr = tid >> 4, c4 = tid & 15;
    const int r0 = tr * 64, c0 = tc * 64;
#pragma unroll
    for (int q = 0; q < 4; q++) {
        int r = rr + q * 16;
        float4 v = *(const float4*)(src + (size_t)(r0 + r) * C + c0 + c4 * 4);
        ls[r][c4 * 4 + 0] = v.x; ls[r][c4 * 4 + 1] = v.y;
        ls[r][c4 * 4 + 2] = v.z; ls[r][c4 * 4 + 3] = v.w;
    }
    __syncthreads();
#pragma unroll
    for (int q = 0; q < 4; q++) {
        int c = rr + q * 16;
        ushort4 o;
        o.x = f2h(ls[c4 * 4 + 0][c]);
        o.y = f2h(ls[c4 * 4 + 1][c]);
        o.z = f2h(ls[c4 * 4 + 2][c]);
        o.w = f2h(ls[c4 * 4 + 3][c]);
        *(ushort4*)(dst + (size_t)(c0 + c) * R + r0 + c4 * 4) = o;
    }
}

// ===========================================================================
// f16 MFMA GEMM: out = A[M,K] @ WT[N,K]^T. 128x64 tile, 4 waves, dbuf LDS.
// RKV==1: z in {0,1,2} picks (xr,xk,xv) + pack slot scatter; RKV==0: f32 out.
// ===========================================================================
template <int RKV>
__global__ __launch_bounds__(256) void mgemm_k(
    const unsigned short* __restrict__ Abase, const unsigned short* __restrict__ WT,
    float* __restrict__ out, int M, int Ncol, int K)
{
    __shared__ unsigned short Ash[2][128][40];
    __shared__ unsigned short Bsh[2][64][40];
    const int z = RKV ? blockIdx.z : 0;
    const unsigned short* A = Abase + (size_t)z * 2097152;
    const unsigned short* BT = WT + (size_t)z * 1048576;
    const int tid = threadIdx.x;
    const int lane = tid & 63, wid = tid >> 6;
    const int wr = wid >> 1, wc = wid & 1;
    const int bm = blockIdx.y * 128, bn = blockIdx.x * 64;
    const int l15 = lane & 15, lk = lane >> 4;
    const int srow = tid >> 2, skc = tid & 3;

    f32x4 acc[4][2];
#pragma unroll
    for (int i = 0; i < 4; i++)
#pragma unroll
        for (int j = 0; j < 2; j++) acc[i][j] = (f32x4){0.f, 0.f, 0.f, 0.f};

    uint4 ra0, ra1, rb0;
    const size_t arow = (size_t)(bm + srow) * K + skc * 8;
    const size_t brow = (size_t)(bn + srow) * K + skc * 8;

#define LOADG(k0)                                                  \
    ra0 = *(const uint4*)(A + arow + (k0));                        \
    ra1 = *(const uint4*)(A + arow + (size_t)64 * K + (k0));       \
    rb0 = *(const uint4*)(BT + brow + (k0));
#define WRITEL(buf)                                                \
    *(uint4*)&Ash[buf][srow][skc * 8] = ra0;                       \
    *(uint4*)&Ash[buf][srow + 64][skc * 8] = ra1;                  \
    *(uint4*)&Bsh[buf][srow][skc * 8] = rb0;

    LOADG(0)
    WRITEL(0)
    __syncthreads();

    int cur = 0;
    for (int k0 = 0; k0 < K; k0 += 32) {
        const bool pf = (k0 + 32 < K);
        if (pf) { LOADG(k0 + 32) }
        half8 af[4], bf[2];
#pragma unroll
        for (int m = 0; m < 4; m++)
            af[m] = *(const half8*)&Ash[cur][wr * 64 + m * 16 + l15][lk * 8];
#pragma unroll
        for (int n = 0; n < 2; n++)
            bf[n] = *(const half8*)&Bsh[cur][wc * 32 + n * 16 + l15][lk * 8];
#pragma unroll
        for (int m = 0; m < 4; m++)
#pragma unroll
            for (int n = 0; n < 2; n++)
                acc[m][n] = __builtin_amdgcn_mfma_f32_16x16x32_f16(af[m], bf[n], acc[m][n], 0, 0, 0);
        if (pf) { WRITEL(cur ^ 1) }
        __syncthreads();
        cur ^= 1;
    }
#undef LOADG
#undef WRITEL

    const int slot = (z == 0) ? SL_R : (z == 1) ? SL_K : SL_V;
#pragma unroll
    for (int m = 0; m < 4; m++) {
#pragma unroll
        for (int n = 0; n < 2; n++) {
            int col = bn + wc * 32 + n * 16 + l15;
#pragma unroll
            for (int r = 0; r < 4; r++) {
                int row = bm + wr * 64 + m * 16 + lk * 4 + r;
                float cval = acc[m][n][r];
                if (RKV == 0) {
                    out[(size_t)row * Ncol + col] = cval;
                } else {
                    int b = row >> 10, t = row & (Tt - 1);
                    int h = col >> 6, nn2 = col & 63;
                    out[((size_t)(b * Hh + h) * Tt + t) * PACKW + slot * Nn + nn2] = cval;
                }
            }
        }
    }
}

// ===========================================================================
// low-rank stage 1 (fused w/a/g): h1[2048][256] f16.
// grid (4,16): bx=0 -> tanh(xw@w1), bx=1 -> xa@a1, bx=2,3 -> sigmoid(xg@g1)
// ===========================================================================
__global__ __launch_bounds__(256) void lr1_k(
    const unsigned short* __restrict__ xf, const unsigned short* __restrict__ wts,
    unsigned short* __restrict__ h1)
{
    __shared__ unsigned short Ash[2][128][40];
    __shared__ unsigned short Bsh[2][64][40];
    const int bx = blockIdx.x;
    const unsigned short* A = xf + (size_t)(bx == 0 ? 3 : bx == 1 ? 4 : 5) * 2097152;
    const unsigned short* BT = wts + (bx == 0 ? 0 : bx == 1 ? 65536 : 131072 + (bx - 2) * 65536);
    const int colbase = bx * 64;
    const int K = 1024;
    const int tid = threadIdx.x;
    const int lane = tid & 63, wid = tid >> 6;
    const int wr = wid >> 1, wc = wid & 1;
    const int bm = blockIdx.y * 128;
    const int l15 = lane & 15, lk = lane >> 4;
    const int srow = tid >> 2, skc = tid & 3;

    f32x4 acc[4][2];
#pragma unroll
    for (int i = 0; i < 4; i++)
#pragma unroll
        for (int j = 0; j < 2; j++) acc[i][j] = (f32x4){0.f, 0.f, 0.f, 0.f};

    uint4 ra0, ra1, rb0;
    const size_t arow = (size_t)(bm + srow) * K + skc * 8;
    const size_t brow = (size_t)srow * K + skc * 8;

#define LOADG(k0)                                                  \
    ra0 = *(const uint4*)(A + arow + (k0));                        \
    ra1 = *(const uint4*)(A + arow + (size_t)64 * K + (k0));       \
    rb0 = *(const uint4*)(BT + brow + (k0));
#define WRITEL(buf)                                                \
    *(uint4*)&Ash[buf][srow][skc * 8] = ra0;                       \
    *(uint4*)&Ash[buf][srow + 64][skc * 8] = ra1;                  \
    *(uint4*)&Bsh[buf][srow][skc * 8] = rb0;

    LOADG(0)
    WRITEL(0)
    __syncthreads();

    int cur = 0;
    for (int k0 = 0; k0 < K; k0 += 32) {
        const bool pf = (k0 + 32 < K);
        if (pf) { LOADG(k0 + 32) }
        half8 af[4], bf[2];
#pragma unroll
        for (int m = 0; m < 4; m++)
            af[m] = *(const half8*)&Ash[cur][wr * 64 + m * 16 + l15][lk * 8];
#pragma unroll
        for (int n = 0; n < 2; n++)
            bf[n] = *(const half8*)&Bsh[cur][wc * 32 + n * 16 + l15][lk * 8];
#pragma unroll
        for (int m = 0; m < 4; m++)
#pragma unroll
            for (int n = 0; n < 2; n++)
                acc[m][n] = __builtin_amdgcn_mfma_f32_16x16x32_f16(af[m], bf[n], acc[m][n], 0, 0, 0);
        if (pf) { WRITEL(cur ^ 1) }
        __syncthreads();
        cur ^= 1;
    }
#undef LOADG
#undef WRITEL

#pragma unroll
    for (int m = 0; m < 4; m++) {
#pragma unroll
        for (int n = 0; n < 2; n++) {
            int col = colbase + wc * 32 + n * 16 + l15;
#pragma unroll
            for (int r = 0; r < 4; r++) {
                int row = bm + wr * 64 + m * 16 + lk * 4 + r;
                float c = acc[m][n][r];
                if (bx == 0) c = tanhf(c);
                else if (bx >= 2) c = sigf(c);
                h1[(size_t)row * 256 + col] = f2h(c);
            }
        }
    }
}

// ===========================================================================
// low-rank stage 2: grid (16,16,3).
// z=0: exp(-exp(w0 + h1[:,0:64]@w2)) -> pack SL_W
// z=1: sigmoid(a0 + h1[:,64:128]@a2) -> pack SL_BV
// z=2: h1[:,128:256]@g2 -> gbuf (f32)
// ===========================================================================
__global__ __launch_bounds__(256) void lr2_k(
    const unsigned short* __restrict__ h1, const unsigned short* __restrict__ wts,
    const float* __restrict__ w0, const float* __restrict__ a0,
    float* __restrict__ pack, float* __restrict__ gbuf)
{
    __shared__ unsigned short Ash[128][40];
    __shared__ unsigned short Bsh[64][40];
    const int z = blockIdx.z;
    const int K = (z == 2) ? 128 : 64;
    const int aoff = (z == 0) ? 0 : (z == 1) ? 64 : 128;
    const unsigned short* BT = wts + 262144 + z * 65536;
    const int tid = threadIdx.x;
    const int lane = tid & 63, wid = tid >> 6;
    const int wr = wid >> 1, wc = wid & 1;
    const int bm = blockIdx.y * 128, bn = blockIdx.x * 64;
    const int l15 = lane & 15, lk = lane >> 4;
    const int srow = tid >> 2, skc = tid & 3;

    f32x4 acc[4][2];
#pragma unroll
    for (int i = 0; i < 4; i++)
#pragma unroll
        for (int j = 0; j < 2; j++) acc[i][j] = (f32x4){0.f, 0.f, 0.f, 0.f};

    for (int k0 = 0; k0 < K; k0 += 32) {
        uint4 ra0 = *(const uint4*)(h1 + (size_t)(bm + srow) * 256 + aoff + k0 + skc * 8);
        uint4 ra1 = *(const uint4*)(h1 + (size_t)(bm + srow + 64) * 256 + aoff + k0 + skc * 8);
        uint4 rb0 = *(const uint4*)(BT + (size_t)(bn + srow) * K + k0 + skc * 8);
        *(uint4*)&Ash[srow][skc * 8] = ra0;
        *(uint4*)&Ash[srow + 64][skc * 8] = ra1;
        *(uint4*)&Bsh[srow][skc * 8] = rb0;
        __syncthreads();
        half8 af[4], bf[2];
#pragma unroll
        for (int m = 0; m < 4; m++)
            af[m] = *(const half8*)&Ash[wr * 64 + m * 16 + l15][lk * 8];
#pragma unroll
        for (int n = 0; n < 2; n++)
            bf[n] = *(const half8*)&Bsh[wc * 32 + n * 16 + l15][lk * 8];
#pragma unroll
        for (int m = 0; m < 4; m++)
#pragma unroll
            for (int n = 0; n < 2; n++)
                acc[m][n] = __builtin_amdgcn_mfma_f32_16x16x32_f16(af[m], bf[n], acc[m][n], 0, 0, 0);
        __syncthreads();
    }

#pragma unroll
    for (int m = 0; m < 4; m++) {
#pragma unroll
        for (int n = 0; n < 2; n++) {
            int col = bn + wc * 32 + n * 16 + l15;
#pragma unroll
            for (int r = 0; r < 4; r++) {
                int row = bm + wr * 64 + m * 16 + lk * 4 + r;
                float c = acc[m][n][r];
                int b = row >> 10, t = row & (Tt - 1);
                int h = col >> 6, nn2 = col & 63;
                if (z == 0) {
                    pack[((size_t)(b * Hh + h) * Tt + t) * PACKW + SL_W * Nn + nn2] = expf(-expf(w0[col] + c));
                } else if (z == 1) {
                    pack[((size_t)(b * Hh + h) * Tt + t) * PACKW + SL_BV * Nn + nn2] = sigf(a0[col] + c);
                } else {
                    gbuf[(size_t)row * Cc + col] = c;
                }
            }
        }
    }
}

// ===========================================================================
// prep: kk normalize etc
// ===========================================================================
__global__ __launch_bounds__(256) void prep_k(float* __restrict__ pk,
                                              const float* __restrict__ k_k,
                                              const float* __restrict__ k_a)
{
    int inst = blockIdx.x * 4 + (threadIdx.x >> 6);
    int lane = threadIdx.x & 63;
    int b = inst >> 14;
    int rem = inst & 16383;
    int t = rem >> 4;
    int h = rem & 15;
    size_t base = ((size_t)(b * Hh + h) * Tt + t) * PACKW;
    int c = h * 64 + lane;
    float kraw = pk[base + SL_K * 64 + lane];
    float a = pk[base + SL_BV * 64 + lane];
    float kkv = kraw * k_k[c];
    float ss = kkv * kkv;
#pragma unroll
    for (int m = 1; m < 64; m <<= 1) ss += __shfl_xor(ss, m);
    float kkn = kkv / fmaxf(sqrtf(ss), 1e-12f);
    pk[base + SL_NK * 64 + lane] = -kkn;
    pk[base + SL_BV * 64 + lane] = kkn * a;
    pk[base + SL_K * 64 + lane] = kraw * (1.f + (a - 1.f) * k_a[c]);
}

// ===========================================================================
// WKV scan v6: 512 one-wave blocks, 4 rows/wave, 8-deep ASM register ring
// (volatile global_load_dwordx4 + counted vmcnt + sched_barrier), DPP red16.
// ===========================================================================
template <int C>
__device__ __forceinline__ float dppmov(float x) {
    return __int_as_float(__builtin_amdgcn_mov_dpp(__float_as_int(x), C, 0xF, 0xF, 1));
}
__device__ __forceinline__ float red16(float v) {
    v += dppmov<0xB1>(v);   // quad_perm xor1
    v += dppmov<0x4E>(v);   // quad_perm xor2
    v += dppmov<0x141>(v);  // row_half_mirror
    v += dppmov<0x140>(v);  // row_mirror
    return v;
}

struct Slot { f32x4 r, w, k, n, b; float v; };

__device__ __forceinline__ void stepf6(f32x4& S, const Slot& f, int jb, float* optr)
{
    float sa = fmaf(S[3], f.n[3], fmaf(S[2], f.n[2], fmaf(S[1], f.n[1], S[0] * f.n[0])));
    sa = red16(sa);
    S[0] = fmaf(S[0], f.w[0], fmaf(sa, f.b[0], f.v * f.k[0]));
    S[1] = fmaf(S[1], f.w[1], fmaf(sa, f.b[1], f.v * f.k[1]));
    S[2] = fmaf(S[2], f.w[2], fmaf(sa, f.b[2], f.v * f.k[2]));
    S[3] = fmaf(S[3], f.w[3], fmaf(sa, f.b[3], f.v * f.k[3]));
    float ot = fmaf(S[3], f.r[3], fmaf(S[2], f.r[2], fmaf(S[1], f.r[1], S[0] * f.r[0])));
    ot = red16(ot);
    if (jb == 0) *optr = ot;
}

__global__ __launch_bounds__(64, 1) void wkv_k(const float* __restrict__ pk, float* __restrict__ o)
{
    const int bx = blockIdx.x;          // 0..511
    const int xcd = bx & 7;
    const int ix = bx >> 3;             // 0..63
    const int bh = ((ix >> 4) << 3) | xcd;
    const int rg = ix & 15;
    const int lane = threadIdx.x;
    const int ri = lane >> 4, jb = lane & 15, j0 = jb * 4;
    const int i = rg * 4 + ri;
    const int b = bh >> 4, h = bh & 15;
    const float* pb = pk + (size_t)bh * Tt * PACKW;
    float* ob = o + (size_t)b * Tt * Cc + h * 64 + i;

    Slot sl[8];
    const float* p1 = pb + j0;
    const float* p2 = pb + SL_V * 64 + i;

    // offsets within a step (bytes): r=0, w=256, k=512, nk=1024, bv=1280
#define ISSUE(s, q1v, q2v)                                                                                \
    asm volatile("global_load_dwordx4 %0, %1, off"             : "=v"(sl[s].r) : "v"(q1v) : "memory");    \
    asm volatile("global_load_dwordx4 %0, %1, off offset:256"  : "=v"(sl[s].w) : "v"(q1v) : "memory");    \
    asm volatile("global_load_dwordx4 %0, %1, off offset:512"  : "=v"(sl[s].k) : "v"(q1v) : "memory");    \
    asm volatile("global_load_dwordx4 %0, %1, off offset:1024" : "=v"(sl[s].n) : "v"(q1v) : "memory");    \
    asm volatile("global_load_dwordx4 %0, %1, off offset:1280" : "=v"(sl[s].b) : "v"(q1v) : "memory");    \
    asm volatile("global_load_dword %0, %1, off"               : "=v"(sl[s].v) : "v"(q2v) : "memory");

    // prologue: slots 0..7 <- steps 0..7  (48 loads in flight)
    ISSUE(0, p1 + 0 * PACKW, p2 + 0 * PACKW)
    ISSUE(1, p1 + 1 * PACKW, p2 + 1 * PACKW)
    ISSUE(2, p1 + 2 * PACKW, p2 + 2 * PACKW)
    ISSUE(3, p1 + 3 * PACKW, p2 + 3 * PACKW)
    ISSUE(4, p1 + 4 * PACKW, p2 + 4 * PACKW)
    ISSUE(5, p1 + 5 * PACKW, p2 + 5 * PACKW)
    ISSUE(6, p1 + 6 * PACKW, p2 + 6 * PACKW)
    ISSUE(7, p1 + 7 * PACKW, p2 + 7 * PACKW)

    const float* q1 = p1 + 8 * PACKW;
    const float* q2 = p2 + 8 * PACKW;
    f32x4 S = (f32x4){0.f, 0.f, 0.f, 0.f};

#define STEP(u)                                                          \
    asm volatile("s_waitcnt vmcnt(42)" ::: "memory");                    \
    __builtin_amdgcn_sched_barrier(0);                                   \
    stepf6(S, sl[u], jb, ob + (size_t)(t0 + (u)) * Cc);                  \
    ISSUE(u, q1, q2)                                                     \
    if (t0 + (u) + 9 < Tt) { q1 += PACKW; q2 += PACKW; }

    for (int t0 = 0; t0 < Tt; t0 += 8) {
        STEP(0) STEP(1) STEP(2) STEP(3) STEP(4) STEP(5) STEP(6) STEP(7)
    }
#undef STEP
#undef ISSUE
}

// ===========================================================================
// post: GroupNorm + rkv + rosa gate + *g -> f16 activation
// ===========================================================================
__global__ __launch_bounds__(256) void post_k(
    const float* __restrict__ o, const float* __restrict__ pk, const float* __restrict__ gbuf,
    const float* __restrict__ r_k, const float* __restrict__ ln_w, const float* __restrict__ ln_b,
    const int* __restrict__ ids, const float* __restrict__ emb, const float* __restrict__ rgate,
    unsigned short* __restrict__ outh)
{
    __shared__ float sred[4];
    const int bt = blockIdx.x;
    const int b = bt >> 10, t = bt & 1023;
    const int tid = threadIdx.x;
    const int c0 = tid * 4;
    const int h = tid >> 4;
    const int nn = c0 & 63;

    float4 o4 = *(const float4*)(o + (size_t)bt * Cc + c0);
    float s = o4.x + o4.y + o4.z + o4.w;
    float ss = o4.x * o4.x + o4.y * o4.y + o4.z * o4.z + o4.w * o4.w;
#pragma unroll
    for (int m = 1; m < 16; m <<= 1) { s += __shfl_xor(s, m); ss += __shfl_xor(ss, m); }
    float mu = s * (1.f / 64.f);
    float inv = rsqrtf(ss * (1.f / 64.f) - mu * mu + 0.00064f);

    size_t pbase = ((size_t)(b * Hh + h) * Tt + t) * PACKW;
    float4 r4 = *(const float4*)(pk + pbase + SL_R * 64 + nn);
    float4 k4 = *(const float4*)(pk + pbase + SL_K * 64 + nn);
    float4 v4 = *(const float4*)(pk + pbase + SL_V * 64 + nn);
    float4 q4 = *(const float4*)(r_k + h * 64 + nn);
    float dot = r4.x * k4.x * q4.x + r4.y * k4.y * q4.y + r4.z * k4.z * q4.z + r4.w * k4.w * q4.w;
#pragma unroll
    for (int m = 1; m < 16; m <<= 1) dot += __shfl_xor(dot, m);

    float4 lw = *(const float4*)(ln_w + c0);
    float4 lb = *(const float4*)(ln_b + c0);
    float e0 = (o4.x - mu) * inv * lw.x + lb.x + dot * v4.x;
    float e1 = (o4.y - mu) * inv * lw.y + lb.y + dot * v4.y;
    float e2 = (o4.z - mu) * inv * lw.z + lb.z + dot * v4.z;
    float e3 = (o4.w - mu) * inv * lw.w + lb.w + dot * v4.w;

    float4 rg4 = *(const float4*)(rgate + c0);
    float gp = sigf(e0 * rg4.x) + sigf(e1 * rg4.y) + sigf(e2 * rg4.z) + sigf(e3 * rg4.w);
#pragma unroll
    for (int m = 1; m < 64; m <<= 1) gp += __shfl_xor(gp, m);
    if ((tid & 63) == 0) sred[tid >> 6] = gp;
    __syncthreads();
    float gate = (sred[0] + sred[1] + sred[2] + sred[3]) * (1.f / 1024.f);

    const int id = ids[bt];
    float4 em = *(const float4*)(emb + (size_t)id * Cc + c0);
    float4 g4 = *(const float4*)(gbuf + (size_t)bt * Cc + c0);
    ushort4 h4;
    h4.x = f2h((e0 * (1.f - gate) + em.x * gate) * g4.x);
    h4.y = f2h((e1 * (1.f - gate) + em.y * gate) * g4.y);
    h4.z = f2h((e2 * (1.f - gate) + em.z * gate) * g4.z);
    h4.w = f2h((e3 * (1.f - gate) + em.w * gate) * g4.w);
    *(ushort4*)(outh + (size_t)bt * Cc + c0) = h4;
}

// ===========================================================================
extern "C" void kernel_launch(void* const* d_in, const int* in_sizes, int n_in,
                              void* d_out, int out_size, void* d_ws, size_t ws_size,
                              hipStream_t stream)
{
    (void)in_sizes; (void)n_in; (void)out_size; (void)ws_size;
    const float* x    = (const float*)d_in[0];
    const int*   ids  = (const int*)d_in[1];
    const float* x_r  = (const float*)d_in[2];
    const float* x_w  = (const float*)d_in[3];
    const float* x_k  = (const float*)d_in[4];
    const float* x_v  = (const float*)d_in[5];
    const float* x_a  = (const float*)d_in[6];
    const float* x_g  = (const float*)d_in[7];
    const float* w0   = (const float*)d_in[8];
    const float* a0   = (const float*)d_in[9];
    const float* w1   = (const float*)d_in[11];
    const float* w2   = (const float*)d_in[12];
    const float* a1   = (const float*)d_in[13];
    const float* a2   = (const float*)d_in[14];
    const float* g1   = (const float*)d_in[17];
    const float* g2   = (const float*)d_in[18];
    const float* k_k  = (const float*)d_in[19];
    const float* k_a  = (const float*)d_in[20];
    const float* r_k  = (const float*)d_in[21];
    const float* Wr   = (const float*)d_in[22];
    const float* Wk   = (const float*)d_in[23];
    const float* Wv   = (const float*)d_in[24];
    const float* Wo   = (const float*)d_in[25];
    const float* ln_w = (const float*)d_in[26];
    const float* ln_b = (const float*)d_in[27];
    const float* emb  = (const float*)d_in[28];
    const float* rg   = (const float*)d_in[29];

    float* ws = (float*)d_ws;
    float* pack = ws;                                          // 12,582,912 f
    float* obuf = pack + (size_t)12582912;                     // 2,097,152 f
    float* gbuf = obuf + (size_t)2097152;                      // 2,097,152 f
    unsigned short* xf  = (unsigned short*)(gbuf + (size_t)2097152);  // 6 x 2,097,152 u16
    unsigned short* wt  = xf + (size_t)6 * 2097152;            // 4 x 1,048,576 u16
    unsigned short* wts = wt + (size_t)4 * 1048576;            // 524,288 u16
    unsigned short* h1  = wts + (size_t)524288;                // 524,288 u16
    unsigned short* obh = xf;   // final activation aliases xr (dead after R proj)

    dim3 blk(256);

    wtrans_k<<<dim3(16, 16, 4), blk, 0, stream>>>(Wr, Wk, Wv, Wo, wt);
    tr6_k<<<dim3(128), blk, 0, stream>>>(w1, a1, g1, w2, a2, g2, wts);
    mixcast_k<<<dim3(2048), blk, 0, stream>>>(x, x_r, x_k, x_v, x_w, x_a, x_g, xf);

    // r, k, v projections (merged z) -> pack slots
    mgemm_k<1><<<dim3(Cc / 64, Mtot / 128, 3), blk, 0, stream>>>(xf, wt, pack, Mtot, Cc, Cc);
    // low-rank chains
    lr1_k<<<dim3(4, 16), blk, 0, stream>>>(xf, wts, h1);
    lr2_k<<<dim3(16, 16, 3), blk, 0, stream>>>(h1, wts, w0, a0, pack, gbuf);

    prep_k<<<dim3(Bb * Tt * Hh / 4), blk, 0, stream>>>(pack, k_k, k_a);
    wkv_k<<<dim3(512), dim3(64), 0, stream>>>(pack, obuf);
    post_k<<<dim3(Mtot), blk, 0, stream>>>(obuf, pack, gbuf, r_k, ln_w, ln_b, ids, emb, rg, obh);
    mgemm_k<0><<<dim3(Cc / 64, Mtot / 128, 1), blk, 0, stream>>>(obh, wt + (size_t)3 * 1048576, (float*)d_out, Mtot, Cc, Cc);
}